// Round 8
// baseline (373.690 us; speedup 1.0000x reference)
//
#include <hip/hip_runtime.h>
#include <hip/hip_bf16.h>
#include <math.h>

#define N_NODES 10000
#define N_EDGES 160000
#define F 128
#define TE 128        // CSR positions per block in fused MLP+gather
#define HS 72         // fp16 row stride for h tiles in LDS (bank-uniform)
#define JP 516        // layer-4 stage row stride (fp16)

typedef _Float16 v8h __attribute__((ext_vector_type(8)));
typedef _Float16 v4h __attribute__((ext_vector_type(4)));
typedef float    v4f __attribute__((ext_vector_type(4)));

__device__ __forceinline__ float nsilu(float x) {
    return 1.679177f * (x / (1.0f + expf(-x)));
}

__device__ __forceinline__ void fma4(float4& a, float s, const float4& b) {
    a.x = fmaf(s, b.x, a.x); a.y = fmaf(s, b.y, a.y);
    a.z = fmaf(s, b.z, a.z); a.w = fmaf(s, b.w, a.w);
}

__device__ __forceinline__ int species_of(int n, const int* __restrict__ counts) {
    int c0 = counts[0];
    int c01 = c0 + counts[1];
    int c012 = c01 + counts[2];
    return (n >= c0) + (n >= c01) + (n >= c012);
}

// ---------------------------------------------------------------------------
// k_setup: fused degree-count + weight prep (fp16 n-major) + input prep.
// ---------------------------------------------------------------------------
__global__ __launch_bounds__(256) void k_setup(
    const int* __restrict__ receivers, int* __restrict__ deg,
    const float* __restrict__ W2, const float* __restrict__ W3,
    const float* __restrict__ W4, const float* __restrict__ b4,
    const float* __restrict__ Wup_s, const float* __restrict__ Wup_v,
    const float* __restrict__ Wz, const float* __restrict__ Wds,
    const float* __restrict__ Wdv, const float* __restrict__ Wpost,
    _Float16* __restrict__ W2t, _Float16* __restrict__ W3t,
    _Float16* __restrict__ W4t, float* __restrict__ b4p,
    _Float16* __restrict__ Wup_s_t, _Float16* __restrict__ Wup_v_t,
    _Float16* __restrict__ Wz_t, _Float16* __restrict__ Wds_t,
    _Float16* __restrict__ Wdv_t, _Float16* __restrict__ Wpost_t,
    const float* __restrict__ ns, const float* __restrict__ nv,
    _Float16* __restrict__ ns16, _Float16* __restrict__ nv16)
{
    int gidx = blockIdx.x * 256 + threadIdx.x;
    if (gidx < N_EDGES) {
        atomicAdd(&deg[receivers[gidx]], 1);
        return;
    }
    int idx = gidx - N_EDGES;
    if (idx < 221696) {
        if (idx < 4096) {                            // W2t[u][k]
            int u = idx >> 6, k = idx & 63;
            W2t[idx] = (_Float16)W2[k * 64 + u];
        } else if (idx < 8192) {                     // W3t
            int j = idx - 4096;
            int u = j >> 6, k = j & 63;
            W3t[j] = (_Float16)W3[k * 64 + u];
        } else if (idx < 40960) {                    // W4t[g_new][k], permuted
            int j = idx - 8192;
            int gn = j >> 6, k = j & 63;
            int go = (gn & 3) * 128 + (gn >> 2);
            W4t[j] = (_Float16)W4[k * 512 + go];
        } else if (idx < 41472) {                    // b4p
            int j = idx - 40960;
            int go = (j & 3) * 128 + (j >> 2);
            b4p[j] = b4[go];
        } else if (idx < 57856) {                    // Wup_s_t[g][f]
            int j = idx - 41472;
            int g = j >> 7, f = j & 127;
            Wup_s_t[j] = (_Float16)Wup_s[f * 128 + g];
        } else if (idx < 74240) {                    // Wup_v_t
            int j = idx - 57856;
            int g = j >> 7, f = j & 127;
            Wup_v_t[j] = (_Float16)Wup_v[f * 128 + g];
        } else if (idx < 139776) {                   // Wz_t[s][g][f]
            int j = idx - 74240;
            int s = j >> 14, r = j & 16383;
            int g = r >> 7, f = r & 127;
            Wz_t[j] = (_Float16)Wz[s * 16384 + f * 128 + g];
        } else if (idx < 172544) {                   // Wds_t[g][k], K=256
            int j = idx - 139776;
            int g = j >> 8, k = j & 255;
            Wds_t[j] = (_Float16)Wds[k * 128 + g];
        } else if (idx < 205312) {                   // Wdv_t
            int j = idx - 172544;
            int g = j >> 8, k = j & 255;
            Wdv_t[j] = (_Float16)Wdv[k * 128 + g];
        } else {                                     // Wpost_t
            int j = idx - 205312;
            int g = j >> 7, f = j & 127;
            Wpost_t[j] = (_Float16)Wpost[f * 128 + g];
        }
        return;
    }
    int j = idx - 221696;
    if (j < N_NODES * F) {
        ns16[j] = (_Float16)ns[j];
    } else if (j < 4 * N_NODES * F) {
        int j2 = j - N_NODES * F;                    // < 3N*F
        int row = j2 >> 7, f = j2 & 127;
        int n = row / 3, c = row - n * 3;
        nv16[j2] = (_Float16)nv[((size_t)n * F + f) * 3 + c];
    }
}

__global__ __launch_bounds__(1024) void k_scan(const int* __restrict__ deg,
                                               int* __restrict__ offs,
                                               int* __restrict__ cursor) {
    __shared__ int sums[1024];
    const int t = threadIdx.x;
    const int CH = 10;
    int base = t * CH;
    int local[CH];
    int s = 0;
    #pragma unroll
    for (int j = 0; j < CH; ++j) {
        int v = (base + j < N_NODES) ? deg[base + j] : 0;
        local[j] = s;
        s += v;
    }
    sums[t] = s;
    __syncthreads();
    for (int off = 1; off < 1024; off <<= 1) {
        int v = (t >= off) ? sums[t - off] : 0;
        __syncthreads();
        sums[t] += v;
        __syncthreads();
    }
    int carry = (t == 0) ? 0 : sums[t - 1];
    #pragma unroll
    for (int j = 0; j < CH; ++j) {
        int idx = base + j;
        if (idx < N_NODES) {
            int o = carry + local[j];
            offs[idx] = o;
            cursor[idx] = o;
        }
    }
    if (t == 1023) offs[N_NODES] = sums[1023];
}

// k_fill: CSR-permute edge metadata, radial embeddings, and node-id stream.
__global__ __launch_bounds__(256) void k_fill(const int* __restrict__ receivers,
                                              const int* __restrict__ senders,
                                              const float* __restrict__ vectors,
                                              const float* __restrict__ radial,
                                              int* __restrict__ cursor,
                                              float4* __restrict__ yq,
                                              float4* __restrict__ re_csr,
                                              int* __restrict__ nidq) {
    int e = blockIdx.x * 256 + threadIdx.x;
    if (e < N_EDGES) {
        int rcv = receivers[e];
        int pos = atomicAdd(&cursor[rcv], 1);
        float vx = vectors[e * 3 + 0];
        float vy = vectors[e * 3 + 1];
        float vz = vectors[e * 3 + 2];
        float inv = 1.0f / (sqrtf(vx * vx + vy * vy + vz * vz) + 1e-12f);
        float4 y;
        y.x = vx * inv; y.y = vy * inv; y.z = vz * inv;
        y.w = __int_as_float(senders[e]);
        yq[pos] = y;
        nidq[pos] = rcv;
        const float4* rp = (const float4*)(radial + (size_t)e * 8);
        re_csr[pos * 2]     = rp[0];
        re_csr[pos * 2 + 1] = rp[1];
    }
}

// ---------------------------------------------------------------------------
// Generic 128x128 fp16 MFMA GEMM tile; AT = A elem type, OT = out elem type.
// ---------------------------------------------------------------------------
__device__ __forceinline__ v8h loadA8(const _Float16* p) { return *(const v8h*)p; }
__device__ __forceinline__ v8h loadA8(const float* p) {
    float4 x0 = *(const float4*)p;
    float4 x1 = *(const float4*)(p + 4);
    v8h r = {(_Float16)x0.x, (_Float16)x0.y, (_Float16)x0.z, (_Float16)x0.w,
             (_Float16)x1.x, (_Float16)x1.y, (_Float16)x1.z, (_Float16)x1.w};
    return r;
}

template <int K, typename AT, typename OT>
__device__ __forceinline__ void gemm_tile(
    const AT* __restrict__ A, const _Float16* __restrict__ Bg,
    OT* __restrict__ out, int M, int row0, float scale,
    _Float16* Bl, const int* __restrict__ counts, int sp)
{
    const int t = threadIdx.x;
    constexpr int KP = K + 8;
    __syncthreads();
    for (int idx = t; idx < 128 * (K / 8); idx += 256) {
        int g = idx / (K / 8), kk = (idx % (K / 8)) * 8;
        *(v8h*)(Bl + g * KP + kk) = *(const v8h*)(Bg + g * K + kk);
    }
    __syncthreads();

    const int lane = t & 63;
    const int w = t >> 6;
    const int c = lane & 15;
    const int q = lane >> 4;

    v4f acc[2][8];
    #pragma unroll
    for (int mi = 0; mi < 2; ++mi)
        #pragma unroll
        for (int nt = 0; nt < 8; ++nt)
            acc[mi][nt] = (v4f){0.f, 0.f, 0.f, 0.f};

    for (int ch = 0; ch < K / 32; ++ch) {
        v8h a[2];
        #pragma unroll
        for (int mi = 0; mi < 2; ++mi) {
            int r = row0 + (2 * w + mi) * 16 + c;
            r = min(r, M - 1);
            a[mi] = loadA8(A + (size_t)r * K + ch * 32 + q * 8);
        }
        #pragma unroll
        for (int nt = 0; nt < 8; ++nt) {
            v8h b = *(const v8h*)(Bl + (nt * 16 + c) * KP + ch * 32 + q * 8);
            acc[0][nt] = __builtin_amdgcn_mfma_f32_16x16x32_f16(a[0], b, acc[0][nt], 0, 0, 0);
            acc[1][nt] = __builtin_amdgcn_mfma_f32_16x16x32_f16(a[1], b, acc[1][nt], 0, 0, 0);
        }
    }
    #pragma unroll
    for (int mi = 0; mi < 2; ++mi) {
        #pragma unroll
        for (int r = 0; r < 4; ++r) {
            int row = row0 + (2 * w + mi) * 16 + q * 4 + r;
            bool ok = row < M;
            if (ok && sp >= 0) ok = (species_of(row, counts) == sp);
            if (ok) {
                OT* op = out + (size_t)row * 128;
                #pragma unroll
                for (int nt = 0; nt < 8; ++nt)
                    op[nt * 16 + c] = (OT)(acc[mi][nt][r] * scale);
            }
        }
    }
}

// grid (235, 3): y=0 s16 (fp16 out), y=1 v16 (fp16 out, M=3N), y=2 selfc (fp32)
__global__ __launch_bounds__(256) void k_gemm_up(
    const _Float16* __restrict__ ns16, const _Float16* __restrict__ nv16,
    const _Float16* __restrict__ Wup_s_t, const _Float16* __restrict__ Wup_v_t,
    const _Float16* __restrict__ Wz_t, const int* __restrict__ counts,
    _Float16* __restrict__ s16, _Float16* __restrict__ v16,
    float* __restrict__ selfc)
{
    __shared__ _Float16 Bl[128 * 136];
    const int row0 = blockIdx.x * 128;
    const float isf = 0.08838834764831845f;
    if (blockIdx.y == 0) {
        if (row0 >= N_NODES) return;
        gemm_tile<128, _Float16, _Float16>(ns16, Wup_s_t, s16, N_NODES, row0, isf, Bl, counts, -1);
    } else if (blockIdx.y == 1) {
        gemm_tile<128, _Float16, _Float16>(nv16, Wup_v_t, v16, 3 * N_NODES, row0, isf, Bl, counts, -1);
    } else {
        if (row0 >= N_NODES) return;
        int sp0 = species_of(row0, counts);
        int sp1 = species_of(min(row0 + 127, N_NODES - 1), counts);
        for (int sp = sp0; sp <= sp1; ++sp)
            gemm_tile<128, _Float16, float>(ns16, Wz_t + (size_t)sp * 16384, selfc,
                                            N_NODES, row0, isf, Bl, counts, sp);
    }
}

// A is fp32 (atomic-accumulated agg); EPS/sqrt(256) folded into scale.
__global__ __launch_bounds__(256) void k_gemm_down(
    const float* __restrict__ agg_s32, const float* __restrict__ agg_v32,
    const _Float16* __restrict__ Wds_t, const _Float16* __restrict__ Wdv_t,
    const int* __restrict__ counts,
    float* __restrict__ s2, float* __restrict__ v2)
{
    __shared__ _Float16 Bl[128 * 264];
    const int row0 = blockIdx.x * 128;
    const float SC = 0.011048543456039804f;          // EPS / sqrt(256)
    if (blockIdx.y == 0) {
        if (row0 >= N_NODES) return;
        gemm_tile<256, float, float>(agg_s32, Wds_t, s2, N_NODES, row0, SC, Bl, counts, -1);
    } else {
        gemm_tile<256, float, float>(agg_v32, Wdv_t, v2, 3 * N_NODES, row0, SC, Bl, counts, -1);
    }
}

// ---------------------------------------------------------------------------
// FUSED radial MLP + TP + gather. mix tile lives only in LDS.
// Positions are CSR-ordered; node walk is uniform across the block.
// ---------------------------------------------------------------------------
__device__ __forceinline__ void mfma_layer64(
    const _Float16* src, _Float16* dst,
    const _Float16* __restrict__ Wt, const float* __restrict__ b,
    int w, int q, int c)
{
    v8h B[4][2];
    float bias[4];
    #pragma unroll
    for (int nt = 0; nt < 4; ++nt) {
        B[nt][0] = *(const v8h*)(Wt + (nt * 16 + c) * 64 + q * 8);
        B[nt][1] = *(const v8h*)(Wt + (nt * 16 + c) * 64 + 32 + q * 8);
        bias[nt] = b[nt * 16 + c];
    }
    #pragma unroll
    for (int mi = 0; mi < 2; ++mi) {
        int mt = 2 * w + mi;
        v8h a0 = *(const v8h*)(src + (mt * 16 + c) * HS + q * 8);
        v8h a1 = *(const v8h*)(src + (mt * 16 + c) * HS + 32 + q * 8);
        #pragma unroll
        for (int nt = 0; nt < 4; ++nt) {
            v4f acc = {bias[nt], bias[nt], bias[nt], bias[nt]};
            acc = __builtin_amdgcn_mfma_f32_16x16x32_f16(a0, B[nt][0], acc, 0, 0, 0);
            acc = __builtin_amdgcn_mfma_f32_16x16x32_f16(a1, B[nt][1], acc, 0, 0, 0);
            #pragma unroll
            for (int r = 0; r < 4; ++r)
                dst[(mt * 16 + q * 4 + r) * HS + nt * 16 + c] = (_Float16)nsilu(acc[r]);
        }
    }
}

__global__ __launch_bounds__(256) void k_mlp_gather(
    const float* __restrict__ re_csr,
    const float* __restrict__ W1, const float* __restrict__ b1,
    const _Float16* __restrict__ W2t, const float* __restrict__ b2,
    const _Float16* __restrict__ W3t, const float* __restrict__ b3,
    const _Float16* __restrict__ W4t, const float* __restrict__ b4p,
    const float4* __restrict__ yq, const int* __restrict__ nidq,
    const _Float16* __restrict__ s16, const _Float16* __restrict__ v16,
    float* __restrict__ agg_s32, float* __restrict__ agg_v32)
{
    __shared__ float sre[TE * 8];        // layer-1 input; later ly + lnid
    __shared__ _Float16 hA[TE * HS];
    __shared__ _Float16 hB[TE * HS];     // h2; later layer-4 stage [16][JP]

    const int t = threadIdx.x;
    const int p0 = blockIdx.x * TE;

    ((float4*)sre)[t] = ((const float4*)(re_csr + (size_t)p0 * 8))[t];
    __syncthreads();

    // ---- layer 1 (K=8, VALU fp32) -> hA fp16
    {
        const int uslot = t & 15;
        const int egrp = t >> 4;
        const int u0 = uslot * 4;
        float4 w[8];
        #pragma unroll
        for (int k = 0; k < 8; ++k) w[k] = *(const float4*)(W1 + k * 64 + u0);
        float4 bb = *(const float4*)(b1 + u0);
        #pragma unroll
        for (int i = 0; i < 8; ++i) {
            int e = egrp + i * 16;
            const float* rp = sre + e * 8;
            float4 a = bb;
            #pragma unroll
            for (int k = 0; k < 8; ++k) fma4(a, rp[k], w[k]);
            v4h r = {(_Float16)nsilu(a.x), (_Float16)nsilu(a.y),
                     (_Float16)nsilu(a.z), (_Float16)nsilu(a.w)};
            *(v4h*)(hA + e * HS + u0) = r;
        }
    }
    __syncthreads();

    // stage yq + nid into the (now dead) sre region
    float4* ly = (float4*)sre;                       // 128 * 16 B
    int* lnid = (int*)(sre + TE * 4);                // 128 * 4 B
    if (t < TE) ly[t] = yq[p0 + t];
    else if (t < 2 * TE) lnid[t - TE] = nidq[p0 + t - TE];

    const int lane = t & 63;
    const int w = t >> 6;
    const int c = lane & 15;
    const int q = lane >> 4;

    mfma_layer64(hA, hB, W2t, b2, w, q, c);          // layer 2: hA -> hB
    mfma_layer64(hB, hA, W3t, b3, w, q, c);          // layer 3: hB -> hA (h3)
    __syncthreads();                                 // h3 + ly/lnid visible

    // layer-4 B fragments: wave w owns cols [128w, 128w+128)
    v8h B4[8][2];
    float bias4[8];
    #pragma unroll
    for (int j = 0; j < 8; ++j) {
        int g = (8 * w + j) * 16 + c;
        B4[j][0] = *(const v8h*)(W4t + g * 64 + q * 8);
        B4[j][1] = *(const v8h*)(W4t + g * 64 + 32 + q * 8);
        bias4[j] = b4p[g];
    }

    _Float16* stage = hB;                            // [16][JP] = 16.5 KB
    const int f = t & 127;
    const int grp = t >> 7;                          // 0: paths m0,m1; 1: m2,m3
    const float inv_sqrt3 = 0.5773502691896258f;

    float a0 = 0, a1 = 0, a2 = 0, a3 = 0;            // per-(f,grp) accumulators
    int cur = lnid[0];

    for (int mt = 0; mt < 8; ++mt) {
        // ---- compute 16x512 mix tile into LDS stage
        {
            v8h x0 = *(const v8h*)(hA + (mt * 16 + c) * HS + q * 8);
            v8h x1 = *(const v8h*)(hA + (mt * 16 + c) * HS + 32 + q * 8);
            #pragma unroll
            for (int j = 0; j < 8; ++j) {
                v4f acc = {bias4[j], bias4[j], bias4[j], bias4[j]};
                acc = __builtin_amdgcn_mfma_f32_16x16x32_f16(x0, B4[j][0], acc, 0, 0, 0);
                acc = __builtin_amdgcn_mfma_f32_16x16x32_f16(x1, B4[j][1], acc, 0, 0, 0);
                int col = (8 * w + j) * 16 + c;
                #pragma unroll
                for (int r = 0; r < 4; ++r)
                    stage[(q * 4 + r) * JP + col] = (_Float16)acc[r];
            }
        }
        __syncthreads();

        // ---- accumulate TP for these 16 positions (uniform node walk)
        for (int i = 0; i < 16; ++i) {
            int pi = mt * 16 + i;
            int n_i = lnid[pi];
            if (n_i != cur) {                        // uniform flush
                if (grp == 0) {
                    atomicAdd(&agg_s32[(size_t)cur * 256 + f], a0);
                    atomicAdd(&agg_v32[((size_t)cur * 3 + 0) * 256 + f], a1);
                    atomicAdd(&agg_v32[((size_t)cur * 3 + 1) * 256 + f], a2);
                    atomicAdd(&agg_v32[((size_t)cur * 3 + 2) * 256 + f], a3);
                } else {
                    atomicAdd(&agg_s32[(size_t)cur * 256 + 128 + f], a0);
                    atomicAdd(&agg_v32[((size_t)cur * 3 + 0) * 256 + 128 + f], a1);
                    atomicAdd(&agg_v32[((size_t)cur * 3 + 1) * 256 + 128 + f], a2);
                    atomicAdd(&agg_v32[((size_t)cur * 3 + 2) * 256 + 128 + f], a3);
                }
                a0 = a1 = a2 = a3 = 0;
                cur = n_i;
            }
            float4 y = ly[pi];
            int snd = __float_as_int(y.w);
            union { unsigned u; _Float16 h[2]; } mm;
            mm.u = *(const unsigned*)(stage + i * JP + f * 4 + grp * 2);
            float mA = (float)mm.h[0];               // grp0: m0 ; grp1: m2
            float mB = (float)mm.h[1];               // grp0: m1 ; grp1: m3
            if (grp == 0) {
                float sg = (float)s16[(size_t)snd * F + f];
                a0 = fmaf(mA, sg, a0);
                float w1s = mB * sg;
                a1 = fmaf(w1s, y.x, a1);
                a2 = fmaf(w1s, y.y, a2);
                a3 = fmaf(w1s, y.z, a3);
            } else {
                const _Float16* vb = v16 + (size_t)snd * 384;
                float vg0 = (float)vb[f];
                float vg1 = (float)vb[128 + f];
                float vg2 = (float)vb[256 + f];
                float dot = vg0 * y.x + vg1 * y.y + vg2 * y.z;
                a0 = fmaf(mB * inv_sqrt3, dot, a0);
                a1 = fmaf(mA, vg0, a1);
                a2 = fmaf(mA, vg1, a2);
                a3 = fmaf(mA, vg2, a3);
            }
        }
        __syncthreads();                             // before stage overwrite
    }
    // final flush
    if (grp == 0) {
        atomicAdd(&agg_s32[(size_t)cur * 256 + f], a0);
        atomicAdd(&agg_v32[((size_t)cur * 3 + 0) * 256 + f], a1);
        atomicAdd(&agg_v32[((size_t)cur * 3 + 1) * 256 + f], a2);
        atomicAdd(&agg_v32[((size_t)cur * 3 + 2) * 256 + f], a3);
    } else {
        atomicAdd(&agg_s32[(size_t)cur * 256 + 128 + f], a0);
        atomicAdd(&agg_v32[((size_t)cur * 3 + 0) * 256 + 128 + f], a1);
        atomicAdd(&agg_v32[((size_t)cur * 3 + 1) * 256 + 128 + f], a2);
        atomicAdd(&agg_v32[((size_t)cur * 3 + 2) * 256 + 128 + f], a3);
    }
}

// ---------------------------------------------------------------------------
__global__ __launch_bounds__(256) void k_contract(
    const float* __restrict__ s2, const float* __restrict__ v2,
    const float* __restrict__ Wsc, const int* __restrict__ counts,
    _Float16* __restrict__ sc16)
{
    int idx = blockIdx.x * 256 + threadIdx.x;
    int n = idx >> 7, g = idx & 127;
    float s = s2[idx];
    const float* vp = v2 + (size_t)n * 384;
    float a0 = vp[g], a1 = vp[128 + g], a2 = vp[256 + g];
    float vv = a0 * a0 + a1 * a1 + a2 * a2;
    const float* w = Wsc + (size_t)species_of(n, counts) * 640;
    float sc = w[g] * s + w[128 + g] * (s * s) + w[256 + g] * vv
             + w[384 + g] * (s * s * s) + w[512 + g] * (s * vv);
    sc16[idx] = (_Float16)sc;
}

// ---------------------------------------------------------------------------
__global__ __launch_bounds__(256) void k_post(
    const _Float16* __restrict__ sc16, const _Float16* __restrict__ Wpost_t,
    const float* __restrict__ selfc,
    const float* __restrict__ Wro1, const float* __restrict__ Wro2,
    float* __restrict__ out)
{
    __shared__ _Float16 Bl[128 * 136];
    __shared__ float sfeat[128][132];
    __shared__ float shr[128][16];
    const int t = threadIdx.x;
    const int row0 = blockIdx.x * 128;
    const float isf = 0.08838834764831845f;

    for (int idx = t; idx < 128 * 16; idx += 256) {
        int g = idx >> 4, kk = (idx & 15) * 8;
        *(v8h*)(Bl + g * 136 + kk) = *(const v8h*)(Wpost_t + g * 128 + kk);
    }
    __syncthreads();

    const int lane = t & 63;
    const int w = t >> 6;
    const int c = lane & 15;
    const int q = lane >> 4;

    v4f acc[2][8];
    #pragma unroll
    for (int mi = 0; mi < 2; ++mi)
        #pragma unroll
        for (int nt = 0; nt < 8; ++nt)
            acc[mi][nt] = (v4f){0.f, 0.f, 0.f, 0.f};

    for (int ch = 0; ch < 4; ++ch) {
        v8h a[2];
        #pragma unroll
        for (int mi = 0; mi < 2; ++mi) {
            int r = row0 + (2 * w + mi) * 16 + c;
            r = min(r, N_NODES - 1);
            a[mi] = *(const v8h*)(sc16 + (size_t)r * 128 + ch * 32 + q * 8);
        }
        #pragma unroll
        for (int nt = 0; nt < 8; ++nt) {
            v8h b = *(const v8h*)(Bl + (nt * 16 + c) * 136 + ch * 32 + q * 8);
            acc[0][nt] = __builtin_amdgcn_mfma_f32_16x16x32_f16(a[0], b, acc[0][nt], 0, 0, 0);
            acc[1][nt] = __builtin_amdgcn_mfma_f32_16x16x32_f16(a[1], b, acc[1][nt], 0, 0, 0);
        }
    }
    #pragma unroll
    for (int mi = 0; mi < 2; ++mi) {
        #pragma unroll
        for (int r = 0; r < 4; ++r) {
            int row = row0 + (2 * w + mi) * 16 + q * 4 + r;
            int rl = (2 * w + mi) * 16 + q * 4 + r;
            if (row < N_NODES) {
                #pragma unroll
                for (int nt = 0; nt < 8; ++nt) {
                    int col = nt * 16 + c;
                    float feat = acc[mi][nt][r] * isf + selfc[(size_t)row * 128 + col];
                    out[N_NODES + (size_t)row * 128 + col] = feat;
                    sfeat[rl][col] = feat;
                }
            } else {
                #pragma unroll
                for (int nt = 0; nt < 8; ++nt) sfeat[rl][nt * 16 + c] = 0.f;
            }
        }
    }
    __syncthreads();

    for (int idx = t; idx < 2048; idx += 256) {
        int nd = idx >> 4, u = idx & 15;
        float a = 0;
        for (int f = 0; f < 128; f += 4) {
            float4 x = *(const float4*)&sfeat[nd][f];
            a += x.x * Wro1[(f + 0) * 16 + u] + x.y * Wro1[(f + 1) * 16 + u]
               + x.z * Wro1[(f + 2) * 16 + u] + x.w * Wro1[(f + 3) * 16 + u];
        }
        shr[nd][u] = nsilu(a * isf);
    }
    __syncthreads();

    if (t < 128 && row0 + t < N_NODES) {
        float a = 0;
        #pragma unroll
        for (int j = 0; j < 16; ++j) a += shr[t][j] * Wro2[j];
        out[row0 + t] = a * 0.25f;
    }
}

// ---------------------------------------------------------------------------

extern "C" void kernel_launch(void* const* d_in, const int* in_sizes, int n_in,
                              void* d_out, int out_size, void* d_ws, size_t ws_size,
                              hipStream_t stream) {
    const float* vectors      = (const float*)d_in[0];
    const float* node_scalars = (const float*)d_in[1];
    const float* node_vectors = (const float*)d_in[2];
    const float* radial       = (const float*)d_in[3];
    const float* W_up_s       = (const float*)d_in[4];
    const float* W_up_v       = (const float*)d_in[5];
    const float* W1 = (const float*)d_in[6];
    const float* b1 = (const float*)d_in[7];
    const float* W2 = (const float*)d_in[8];
    const float* b2 = (const float*)d_in[9];
    const float* W3 = (const float*)d_in[10];
    const float* b3 = (const float*)d_in[11];
    const float* W4 = (const float*)d_in[12];
    const float* b4 = (const float*)d_in[13];
    const float* Wds  = (const float*)d_in[14];
    const float* Wdv  = (const float*)d_in[15];
    const float* Wz   = (const float*)d_in[16];
    const float* Wsc  = (const float*)d_in[17];
    const float* Wpost= (const float*)d_in[18];
    const float* Wro1 = (const float*)d_in[19];
    const float* Wro2 = (const float*)d_in[20];
    const int* senders   = (const int*)d_in[21];
    const int* receivers = (const int*)d_in[22];
    const int* counts    = (const int*)d_in[23];
    float* out = (float*)d_out;

    const size_t NF = (size_t)N_NODES * F;

    char* base = (char*)d_ws;
    float* s2      = (float*)base;                         // N*128 f32
    float* v2      = s2 + NF;                              // 3N*128 f32
    _Float16* sc16 = (_Float16*)(v2 + 3 * NF);             // N*128 f16
    float4* re_csr = (float4*)(sc16 + NF);                 // E*8 f32
    int* nidq      = (int*)((char*)re_csr + (size_t)N_EDGES * 32);
    float* agg_s32 = (float*)((char*)nidq + ((size_t)N_EDGES * 4 + 12) / 16 * 16 + 16);
    float* agg_v32 = agg_s32 + 2 * NF;                     // [n*3+c][256] f32
    // agg block = N*1024 f32 = 40.96 MB (contiguous for single memset)

    char* p = (char*)(agg_v32 + 6 * NF);
    float4* yq     = (float4*)p;          p += (size_t)N_EDGES * 16;
    _Float16* ns16 = (_Float16*)p;        p += NF * 2;
    _Float16* nv16 = (_Float16*)p;        p += 3 * NF * 2;
    _Float16* s16  = (_Float16*)p;        p += NF * 2;
    _Float16* v16  = (_Float16*)p;        p += 3 * NF * 2;
    float* selfc   = (float*)p;           p += NF * 4;
    int* deg    = (int*)p;                p += N_NODES * 4;
    int* offs   = (int*)p;                p += (N_NODES + 1) * 4 + 12;  // pad
    int* cursor = (int*)p;                p += N_NODES * 4;
    _Float16* W2t = (_Float16*)p;         p += 4096 * 2;
    _Float16* W3t = (_Float16*)p;         p += 4096 * 2;
    _Float16* W4t = (_Float16*)p;         p += 32768 * 2;
    float* b4p    = (float*)p;            p += 512 * 4;
    _Float16* Wup_s_t = (_Float16*)p;     p += 16384 * 2;
    _Float16* Wup_v_t = (_Float16*)p;     p += 16384 * 2;
    _Float16* Wz_t    = (_Float16*)p;     p += 65536 * 2;
    _Float16* Wds_t   = (_Float16*)p;     p += 32768 * 2;
    _Float16* Wdv_t   = (_Float16*)p;     p += 32768 * 2;
    _Float16* Wpost_t = (_Float16*)p;     p += 16384 * 2;

    hipMemsetAsync(deg, 0, N_NODES * sizeof(int), stream);
    hipMemsetAsync(agg_s32, 0, (size_t)N_NODES * 1024 * sizeof(float), stream);

    k_setup<<<21491, 256, 0, stream>>>(
        receivers, deg, W2, W3, W4, b4, W_up_s, W_up_v, Wz, Wds, Wdv, Wpost,
        W2t, W3t, W4t, b4p, Wup_s_t, Wup_v_t, Wz_t, Wds_t, Wdv_t, Wpost_t,
        node_scalars, node_vectors, ns16, nv16);

    k_scan<<<1, 1024, 0, stream>>>(deg, offs, cursor);

    k_fill<<<(N_EDGES + 255) / 256, 256, 0, stream>>>(
        receivers, senders, vectors, radial, cursor, yq, re_csr, nidq);

    k_gemm_up<<<dim3(235, 3), 256, 0, stream>>>(
        ns16, nv16, Wup_s_t, Wup_v_t, Wz_t, counts, s16, v16, selfc);

    k_mlp_gather<<<N_EDGES / TE, 256, 0, stream>>>(
        (const float*)re_csr, W1, b1, W2t, b2, W3t, b3, W4t, b4p,
        yq, nidq, s16, v16, agg_s32, agg_v32);

    k_gemm_down<<<dim3(235, 2), 256, 0, stream>>>(
        agg_s32, agg_v32, Wds_t, Wdv_t, counts, s2, v2);

    k_contract<<<(N_NODES * F) / 256, 256, 0, stream>>>(s2, v2, Wsc, counts, sc16);

    k_post<<<(N_NODES + 127) / 128, 256, 0, stream>>>(
        sc16, Wpost_t, selfc, Wro1, Wro2, out);
}

// Round 9
// 322.569 us; speedup vs baseline: 1.1585x; 1.1585x over previous
//
#include <hip/hip_runtime.h>
#include <hip/hip_bf16.h>
#include <math.h>

#define N_NODES 10000
#define N_EDGES 160000
#define F 128
#define TE 128        // edges per block in k_mlp
#define HS 72         // fp16 row stride for h tiles in LDS

typedef _Float16 v8h __attribute__((ext_vector_type(8)));
typedef _Float16 v4h __attribute__((ext_vector_type(4)));
typedef float    v4f __attribute__((ext_vector_type(4)));

__device__ __forceinline__ float nsilu(float x) {
    return 1.679177f * (x / (1.0f + expf(-x)));
}

__device__ __forceinline__ void fma4(float4& a, float s, const float4& b) {
    a.x = fmaf(s, b.x, a.x); a.y = fmaf(s, b.y, a.y);
    a.z = fmaf(s, b.z, a.z); a.w = fmaf(s, b.w, a.w);
}

__device__ __forceinline__ int species_of(int n, const int* __restrict__ counts) {
    int c0 = counts[0];
    int c01 = c0 + counts[1];
    int c012 = c01 + counts[2];
    return (n >= c0) + (n >= c01) + (n >= c012);
}

// ---------------------------------------------------------------------------
// k_setup: fused degree-count + weight prep (fp16 n-major) + input prep.
// ---------------------------------------------------------------------------
__global__ __launch_bounds__(256) void k_setup(
    const int* __restrict__ receivers, int* __restrict__ deg,
    const float* __restrict__ W2, const float* __restrict__ W3,
    const float* __restrict__ W4, const float* __restrict__ b4,
    const float* __restrict__ Wup_s, const float* __restrict__ Wup_v,
    const float* __restrict__ Wz, const float* __restrict__ Wds,
    const float* __restrict__ Wdv, const float* __restrict__ Wpost,
    _Float16* __restrict__ W2t, _Float16* __restrict__ W3t,
    _Float16* __restrict__ W4t, float* __restrict__ b4p,
    _Float16* __restrict__ Wup_s_t, _Float16* __restrict__ Wup_v_t,
    _Float16* __restrict__ Wz_t, _Float16* __restrict__ Wds_t,
    _Float16* __restrict__ Wdv_t, _Float16* __restrict__ Wpost_t,
    const float* __restrict__ ns, const float* __restrict__ nv,
    _Float16* __restrict__ ns16, _Float16* __restrict__ nv16)
{
    int gidx = blockIdx.x * 256 + threadIdx.x;
    if (gidx < N_EDGES) {
        atomicAdd(&deg[receivers[gidx]], 1);
        return;
    }
    int idx = gidx - N_EDGES;
    if (idx < 221696) {
        if (idx < 4096) {                            // W2t[u][k]
            int u = idx >> 6, k = idx & 63;
            W2t[idx] = (_Float16)W2[k * 64 + u];
        } else if (idx < 8192) {                     // W3t
            int j = idx - 4096;
            int u = j >> 6, k = j & 63;
            W3t[j] = (_Float16)W3[k * 64 + u];
        } else if (idx < 40960) {                    // W4t[g_new][k], permuted
            int j = idx - 8192;
            int gn = j >> 6, k = j & 63;
            int go = (gn & 3) * 128 + (gn >> 2);
            W4t[j] = (_Float16)W4[k * 512 + go];
        } else if (idx < 41472) {                    // b4p
            int j = idx - 40960;
            int go = (j & 3) * 128 + (j >> 2);
            b4p[j] = b4[go];
        } else if (idx < 57856) {                    // Wup_s_t[g][f]
            int j = idx - 41472;
            int g = j >> 7, f = j & 127;
            Wup_s_t[j] = (_Float16)Wup_s[f * 128 + g];
        } else if (idx < 74240) {                    // Wup_v_t
            int j = idx - 57856;
            int g = j >> 7, f = j & 127;
            Wup_v_t[j] = (_Float16)Wup_v[f * 128 + g];
        } else if (idx < 139776) {                   // Wz_t[s][g][f]
            int j = idx - 74240;
            int s = j >> 14, r = j & 16383;
            int g = r >> 7, f = r & 127;
            Wz_t[j] = (_Float16)Wz[s * 16384 + f * 128 + g];
        } else if (idx < 172544) {                   // Wds_t[g][k], K=256
            int j = idx - 139776;
            int g = j >> 8, k = j & 255;
            Wds_t[j] = (_Float16)Wds[k * 128 + g];
        } else if (idx < 205312) {                   // Wdv_t
            int j = idx - 172544;
            int g = j >> 8, k = j & 255;
            Wdv_t[j] = (_Float16)Wdv[k * 128 + g];
        } else {                                     // Wpost_t
            int j = idx - 205312;
            int g = j >> 7, f = j & 127;
            Wpost_t[j] = (_Float16)Wpost[f * 128 + g];
        }
        return;
    }
    int j = idx - 221696;
    if (j < N_NODES * F) {
        ns16[j] = (_Float16)ns[j];
    } else if (j < 4 * N_NODES * F) {
        int j2 = j - N_NODES * F;                    // < 3N*F
        int row = j2 >> 7, f = j2 & 127;
        int n = row / 3, c = row - n * 3;
        nv16[j2] = (_Float16)nv[((size_t)n * F + f) * 3 + c];
    }
}

__global__ __launch_bounds__(1024) void k_scan(const int* __restrict__ deg,
                                               int* __restrict__ offs,
                                               int* __restrict__ cursor) {
    __shared__ int sums[1024];
    const int t = threadIdx.x;
    const int CH = 10;
    int base = t * CH;
    int local[CH];
    int s = 0;
    #pragma unroll
    for (int j = 0; j < CH; ++j) {
        int v = (base + j < N_NODES) ? deg[base + j] : 0;
        local[j] = s;
        s += v;
    }
    sums[t] = s;
    __syncthreads();
    for (int off = 1; off < 1024; off <<= 1) {
        int v = (t >= off) ? sums[t - off] : 0;
        __syncthreads();
        sums[t] += v;
        __syncthreads();
    }
    int carry = (t == 0) ? 0 : sums[t - 1];
    #pragma unroll
    for (int j = 0; j < CH; ++j) {
        int idx = base + j;
        if (idx < N_NODES) {
            int o = carry + local[j];
            offs[idx] = o;
            cursor[idx] = o;
        }
    }
    if (t == 1023) offs[N_NODES] = sums[1023];
}

// k_fill: CSR-permute edge metadata AND the radial embeddings.
__global__ __launch_bounds__(256) void k_fill(const int* __restrict__ receivers,
                                              const int* __restrict__ senders,
                                              const float* __restrict__ vectors,
                                              const float* __restrict__ radial,
                                              int* __restrict__ cursor,
                                              float4* __restrict__ yq,
                                              float4* __restrict__ re_csr) {
    int e = blockIdx.x * 256 + threadIdx.x;
    if (e < N_EDGES) {
        int pos = atomicAdd(&cursor[receivers[e]], 1);
        float vx = vectors[e * 3 + 0];
        float vy = vectors[e * 3 + 1];
        float vz = vectors[e * 3 + 2];
        float inv = 1.0f / (sqrtf(vx * vx + vy * vy + vz * vz) + 1e-12f);
        float4 y;
        y.x = vx * inv; y.y = vy * inv; y.z = vz * inv;
        y.w = __int_as_float(senders[e]);
        yq[pos] = y;
        const float4* rp = (const float4*)(radial + (size_t)e * 8);
        re_csr[pos * 2]     = rp[0];
        re_csr[pos * 2 + 1] = rp[1];
    }
}

// ---------------------------------------------------------------------------
// Generic 128x128 fp16 MFMA GEMM tile; OT = output element type.
// ---------------------------------------------------------------------------
template <int K, typename OT>
__device__ __forceinline__ void gemm_tile(
    const _Float16* __restrict__ A, const _Float16* __restrict__ Bg,
    OT* __restrict__ out, int M, int row0, float scale,
    _Float16* Bl, const int* __restrict__ counts, int sp)
{
    const int t = threadIdx.x;
    constexpr int KP = K + 8;
    __syncthreads();
    for (int idx = t; idx < 128 * (K / 8); idx += 256) {
        int g = idx / (K / 8), kk = (idx % (K / 8)) * 8;
        *(v8h*)(Bl + g * KP + kk) = *(const v8h*)(Bg + g * K + kk);
    }
    __syncthreads();

    const int lane = t & 63;
    const int w = t >> 6;
    const int c = lane & 15;
    const int q = lane >> 4;

    v4f acc[2][8];
    #pragma unroll
    for (int mi = 0; mi < 2; ++mi)
        #pragma unroll
        for (int nt = 0; nt < 8; ++nt)
            acc[mi][nt] = (v4f){0.f, 0.f, 0.f, 0.f};

    for (int ch = 0; ch < K / 32; ++ch) {
        v8h a[2];
        #pragma unroll
        for (int mi = 0; mi < 2; ++mi) {
            int r = row0 + (2 * w + mi) * 16 + c;
            r = min(r, M - 1);
            a[mi] = *(const v8h*)(A + (size_t)r * K + ch * 32 + q * 8);
        }
        #pragma unroll
        for (int nt = 0; nt < 8; ++nt) {
            v8h b = *(const v8h*)(Bl + (nt * 16 + c) * KP + ch * 32 + q * 8);
            acc[0][nt] = __builtin_amdgcn_mfma_f32_16x16x32_f16(a[0], b, acc[0][nt], 0, 0, 0);
            acc[1][nt] = __builtin_amdgcn_mfma_f32_16x16x32_f16(a[1], b, acc[1][nt], 0, 0, 0);
        }
    }
    #pragma unroll
    for (int mi = 0; mi < 2; ++mi) {
        #pragma unroll
        for (int r = 0; r < 4; ++r) {
            int row = row0 + (2 * w + mi) * 16 + q * 4 + r;
            bool ok = row < M;
            if (ok && sp >= 0) ok = (species_of(row, counts) == sp);
            if (ok) {
                OT* op = out + (size_t)row * 128;
                #pragma unroll
                for (int nt = 0; nt < 8; ++nt)
                    op[nt * 16 + c] = (OT)(acc[mi][nt][r] * scale);
            }
        }
    }
}

// grid (235, 3): y=0 s16 (fp16 out), y=1 v16 (fp16 out, M=3N), y=2 selfc (fp32)
__global__ __launch_bounds__(256) void k_gemm_up(
    const _Float16* __restrict__ ns16, const _Float16* __restrict__ nv16,
    const _Float16* __restrict__ Wup_s_t, const _Float16* __restrict__ Wup_v_t,
    const _Float16* __restrict__ Wz_t, const int* __restrict__ counts,
    _Float16* __restrict__ s16, _Float16* __restrict__ v16,
    float* __restrict__ selfc)
{
    __shared__ _Float16 Bl[128 * 136];
    const int row0 = blockIdx.x * 128;
    const float isf = 0.08838834764831845f;
    if (blockIdx.y == 0) {
        if (row0 >= N_NODES) return;
        gemm_tile<128, _Float16>(ns16, Wup_s_t, s16, N_NODES, row0, isf, Bl, counts, -1);
    } else if (blockIdx.y == 1) {
        gemm_tile<128, _Float16>(nv16, Wup_v_t, v16, 3 * N_NODES, row0, isf, Bl, counts, -1);
    } else {
        if (row0 >= N_NODES) return;
        int sp0 = species_of(row0, counts);
        int sp1 = species_of(min(row0 + 127, N_NODES - 1), counts);
        for (int sp = sp0; sp <= sp1; ++sp)
            gemm_tile<128, float>(ns16, Wz_t + (size_t)sp * 16384, selfc,
                                  N_NODES, row0, isf, Bl, counts, sp);
    }
}

__global__ __launch_bounds__(256) void k_gemm_down(
    const _Float16* __restrict__ agg_s16, const _Float16* __restrict__ agg_v16,
    const _Float16* __restrict__ Wds_t, const _Float16* __restrict__ Wdv_t,
    const int* __restrict__ counts,
    float* __restrict__ s2, float* __restrict__ v2)
{
    __shared__ _Float16 Bl[128 * 264];
    const int row0 = blockIdx.x * 128;
    if (blockIdx.y == 0) {
        if (row0 >= N_NODES) return;
        gemm_tile<256, float>(agg_s16, Wds_t, s2, N_NODES, row0, 1.0f, Bl, counts, -1);
    } else {
        gemm_tile<256, float>(agg_v16, Wdv_t, v2, 3 * N_NODES, row0, 1.0f, Bl, counts, -1);
    }
}

// ---------------------------------------------------------------------------
// Radial MLP via fp16 MFMA, TRANSPOSED epilogues: output-channel on the M
// axis makes each lane's 4 acc values contiguous -> v4h stores (A/B fragment
// layouts are identical for 16x16x32, so swapping operands transposes D with
// the same loads and identical numerics).
// ---------------------------------------------------------------------------
__device__ __forceinline__ void mfma_layer64(
    const _Float16* src, _Float16* dst,
    const _Float16* __restrict__ Wt, const float* __restrict__ b,
    int w, int q, int c)
{
    v8h A[4][2];
    v4f bias[4];
    #pragma unroll
    for (int ut = 0; ut < 4; ++ut) {
        A[ut][0] = *(const v8h*)(Wt + (ut * 16 + c) * 64 + q * 8);
        A[ut][1] = *(const v8h*)(Wt + (ut * 16 + c) * 64 + 32 + q * 8);
        float4 bb = *(const float4*)(b + ut * 16 + q * 4);
        bias[ut] = (v4f){bb.x, bb.y, bb.z, bb.w};
    }
    #pragma unroll
    for (int ei = 0; ei < 2; ++ei) {
        int et = 2 * w + ei;
        v8h h0 = *(const v8h*)(src + (et * 16 + c) * HS + q * 8);
        v8h h1 = *(const v8h*)(src + (et * 16 + c) * HS + 32 + q * 8);
        #pragma unroll
        for (int ut = 0; ut < 4; ++ut) {
            v4f acc = bias[ut];
            acc = __builtin_amdgcn_mfma_f32_16x16x32_f16(A[ut][0], h0, acc, 0, 0, 0);
            acc = __builtin_amdgcn_mfma_f32_16x16x32_f16(A[ut][1], h1, acc, 0, 0, 0);
            v4h r = {(_Float16)nsilu(acc[0]), (_Float16)nsilu(acc[1]),
                     (_Float16)nsilu(acc[2]), (_Float16)nsilu(acc[3])};
            *(v4h*)(dst + (et * 16 + c) * HS + ut * 16 + q * 4) = r;
        }
    }
}

__global__ __launch_bounds__(256) void k_mlp(
    const float* __restrict__ re_csr,
    const float* __restrict__ W1, const float* __restrict__ b1,
    const _Float16* __restrict__ W2t, const float* __restrict__ b2,
    const _Float16* __restrict__ W3t, const float* __restrict__ b3,
    const _Float16* __restrict__ W4t, const float* __restrict__ b4p,
    _Float16* __restrict__ mix)
{
    __shared__ float sre[TE * 8];
    __shared__ _Float16 hA[TE * HS];
    __shared__ _Float16 hB[TE * HS];

    const int t = threadIdx.x;
    const int p0 = blockIdx.x * TE;      // CSR position base

    ((float4*)sre)[t] = ((const float4*)(re_csr + (size_t)p0 * 8))[t];
    __syncthreads();

    {
        const int uslot = t & 15;
        const int egrp = t >> 4;
        const int u0 = uslot * 4;
        float4 w[8];
        #pragma unroll
        for (int k = 0; k < 8; ++k) w[k] = *(const float4*)(W1 + k * 64 + u0);
        float4 bb = *(const float4*)(b1 + u0);
        #pragma unroll
        for (int i = 0; i < 8; ++i) {
            int e = egrp + i * 16;
            const float* rp = sre + e * 8;
            float4 a = bb;
            #pragma unroll
            for (int k = 0; k < 8; ++k) fma4(a, rp[k], w[k]);
            v4h r = {(_Float16)nsilu(a.x), (_Float16)nsilu(a.y),
                     (_Float16)nsilu(a.z), (_Float16)nsilu(a.w)};
            *(v4h*)(hA + e * HS + u0) = r;
        }
    }
    __syncthreads();

    const int lane = t & 63;
    const int w = t >> 6;
    const int c = lane & 15;
    const int q = lane >> 4;

    mfma_layer64(hA, hB, W2t, b2, w, q, c);
    mfma_layer64(hB, hA, W3t, b3, w, q, c);
    __syncthreads();

    // layer 4 (transposed): wave w owns g-tiles [8w, 8w+8)
    v8h A4[8][2];
    v4f bias4[8];
    #pragma unroll
    for (int j = 0; j < 8; ++j) {
        int g0 = (8 * w + j) * 16;
        A4[j][0] = *(const v8h*)(W4t + (g0 + c) * 64 + q * 8);
        A4[j][1] = *(const v8h*)(W4t + (g0 + c) * 64 + 32 + q * 8);
        float4 bb = *(const float4*)(b4p + g0 + q * 4);
        bias4[j] = (v4f){bb.x, bb.y, bb.z, bb.w};
    }
    for (int mt = 0; mt < 8; ++mt) {
        v8h h0 = *(const v8h*)(hA + (mt * 16 + c) * HS + q * 8);
        v8h h1 = *(const v8h*)(hA + (mt * 16 + c) * HS + 32 + q * 8);
        size_t rowbase = (size_t)(p0 + mt * 16 + c) * 512;
        #pragma unroll
        for (int j = 0; j < 8; ++j) {
            v4f acc = bias4[j];
            acc = __builtin_amdgcn_mfma_f32_16x16x32_f16(A4[j][0], h0, acc, 0, 0, 0);
            acc = __builtin_amdgcn_mfma_f32_16x16x32_f16(A4[j][1], h1, acc, 0, 0, 0);
            v4h r = {(_Float16)acc[0], (_Float16)acc[1],
                     (_Float16)acc[2], (_Float16)acc[3]};
            *(v4h*)(mix + rowbase + (8 * w + j) * 16 + q * 4) = r;
        }
    }
}

// ---------------------------------------------------------------------------
// Gather: mix CSR-ordered (sequential). yq chunk-prefetched into LDS.
// ---------------------------------------------------------------------------
__global__ __launch_bounds__(128) void k_gather(
    const _Float16* __restrict__ mix, const float4* __restrict__ yq,
    const _Float16* __restrict__ s16, const _Float16* __restrict__ v16,
    const int* __restrict__ offs,
    _Float16* __restrict__ agg_s16, _Float16* __restrict__ agg_v16)
{
    const int n = blockIdx.x;
    const int f = threadIdx.x;
    const int beg = offs[n], end = offs[n + 1];
    const float inv_sqrt3 = 0.5773502691896258f;
    __shared__ float4 ly[32];

    float as0 = 0, as1 = 0;
    float av00 = 0, av01 = 0, av02 = 0, av10 = 0, av11 = 0, av12 = 0;

    for (int c0 = beg; c0 < end; c0 += 32) {
        int cnt = min(32, end - c0);
        __syncthreads();
        if (f < cnt) ly[f] = yq[c0 + f];
        __syncthreads();
        #pragma unroll 4
        for (int i = 0; i < cnt; ++i) {
            float4 y = ly[i];
            int snd = __float_as_int(y.w);

            union { uint2 u; _Float16 h[4]; } mu;
            mu.u = *(const uint2*)(mix + (size_t)(c0 + i) * 512 + f * 4);
            float m0 = (float)mu.h[0];
            float m1 = (float)mu.h[1];
            float m2 = (float)mu.h[2];
            float m3 = (float)mu.h[3];

            float sg = (float)s16[(size_t)snd * F + f];
            const _Float16* vb = v16 + (size_t)snd * 384;
            float vg0 = (float)vb[f];
            float vg1 = (float)vb[128 + f];
            float vg2 = (float)vb[256 + f];

            as0 += m0 * sg;
            as1 += m3 * (vg0 * y.x + vg1 * y.y + vg2 * y.z) * inv_sqrt3;
            float w1s = m1 * sg;
            av00 += w1s * y.x; av01 += w1s * y.y; av02 += w1s * y.z;
            av10 += m2 * vg0;  av11 += m2 * vg1;  av12 += m2 * vg2;
        }
    }
    const float SC = 0.011048543456039804f;          // EPS / sqrt(256)
    agg_s16[(size_t)n * 256 + f]       = (_Float16)(as0 * SC);
    agg_s16[(size_t)n * 256 + 128 + f] = (_Float16)(as1 * SC);
    _Float16* av = agg_v16 + (size_t)n * 768;
    av[0 * 256 + f]       = (_Float16)(av00 * SC);
    av[0 * 256 + 128 + f] = (_Float16)(av10 * SC);
    av[1 * 256 + f]       = (_Float16)(av01 * SC);
    av[1 * 256 + 128 + f] = (_Float16)(av11 * SC);
    av[2 * 256 + f]       = (_Float16)(av02 * SC);
    av[2 * 256 + 128 + f] = (_Float16)(av12 * SC);
}

// ---------------------------------------------------------------------------
__global__ __launch_bounds__(256) void k_contract(
    const float* __restrict__ s2, const float* __restrict__ v2,
    const float* __restrict__ Wsc, const int* __restrict__ counts,
    _Float16* __restrict__ sc16)
{
    int idx = blockIdx.x * 256 + threadIdx.x;
    int n = idx >> 7, g = idx & 127;
    float s = s2[idx];
    const float* vp = v2 + (size_t)n * 384;
    float a0 = vp[g], a1 = vp[128 + g], a2 = vp[256 + g];
    float vv = a0 * a0 + a1 * a1 + a2 * a2;
    const float* w = Wsc + (size_t)species_of(n, counts) * 640;
    float sc = w[g] * s + w[128 + g] * (s * s) + w[256 + g] * vv
             + w[384 + g] * (s * s * s) + w[512 + g] * (s * vv);
    sc16[idx] = (_Float16)sc;
}

// ---------------------------------------------------------------------------
__global__ __launch_bounds__(256) void k_post(
    const _Float16* __restrict__ sc16, const _Float16* __restrict__ Wpost_t,
    const float* __restrict__ selfc,
    const float* __restrict__ Wro1, const float* __restrict__ Wro2,
    float* __restrict__ out)
{
    __shared__ _Float16 Bl[128 * 136];
    __shared__ float sfeat[128][132];
    __shared__ float shr[128][16];
    const int t = threadIdx.x;
    const int row0 = blockIdx.x * 128;
    const float isf = 0.08838834764831845f;

    for (int idx = t; idx < 128 * 16; idx += 256) {
        int g = idx >> 4, kk = (idx & 15) * 8;
        *(v8h*)(Bl + g * 136 + kk) = *(const v8h*)(Wpost_t + g * 128 + kk);
    }
    __syncthreads();

    const int lane = t & 63;
    const int w = t >> 6;
    const int c = lane & 15;
    const int q = lane >> 4;

    v4f acc[2][8];
    #pragma unroll
    for (int mi = 0; mi < 2; ++mi)
        #pragma unroll
        for (int nt = 0; nt < 8; ++nt)
            acc[mi][nt] = (v4f){0.f, 0.f, 0.f, 0.f};

    for (int ch = 0; ch < 4; ++ch) {
        v8h a[2];
        #pragma unroll
        for (int mi = 0; mi < 2; ++mi) {
            int r = row0 + (2 * w + mi) * 16 + c;
            r = min(r, N_NODES - 1);
            a[mi] = *(const v8h*)(sc16 + (size_t)r * 128 + ch * 32 + q * 8);
        }
        #pragma unroll
        for (int nt = 0; nt < 8; ++nt) {
            v8h b = *(const v8h*)(Bl + (nt * 16 + c) * 136 + ch * 32 + q * 8);
            acc[0][nt] = __builtin_amdgcn_mfma_f32_16x16x32_f16(a[0], b, acc[0][nt], 0, 0, 0);
            acc[1][nt] = __builtin_amdgcn_mfma_f32_16x16x32_f16(a[1], b, acc[1][nt], 0, 0, 0);
        }
    }
    #pragma unroll
    for (int mi = 0; mi < 2; ++mi) {
        #pragma unroll
        for (int r = 0; r < 4; ++r) {
            int row = row0 + (2 * w + mi) * 16 + q * 4 + r;
            int rl = (2 * w + mi) * 16 + q * 4 + r;
            if (row < N_NODES) {
                #pragma unroll
                for (int nt = 0; nt < 8; ++nt) {
                    int col = nt * 16 + c;
                    float feat = acc[mi][nt][r] * isf + selfc[(size_t)row * 128 + col];
                    out[N_NODES + (size_t)row * 128 + col] = feat;
                    sfeat[rl][col] = feat;
                }
            } else {
                #pragma unroll
                for (int nt = 0; nt < 8; ++nt) sfeat[rl][nt * 16 + c] = 0.f;
            }
        }
    }
    __syncthreads();

    for (int idx = t; idx < 2048; idx += 256) {
        int nd = idx >> 4, u = idx & 15;
        float a = 0;
        for (int f = 0; f < 128; f += 4) {
            float4 x = *(const float4*)&sfeat[nd][f];
            a += x.x * Wro1[(f + 0) * 16 + u] + x.y * Wro1[(f + 1) * 16 + u]
               + x.z * Wro1[(f + 2) * 16 + u] + x.w * Wro1[(f + 3) * 16 + u];
        }
        shr[nd][u] = nsilu(a * isf);
    }
    __syncthreads();

    if (t < 128 && row0 + t < N_NODES) {
        float a = 0;
        #pragma unroll
        for (int j = 0; j < 16; ++j) a += shr[t][j] * Wro2[j];
        out[row0 + t] = a * 0.25f;
    }
}

// ---------------------------------------------------------------------------

extern "C" void kernel_launch(void* const* d_in, const int* in_sizes, int n_in,
                              void* d_out, int out_size, void* d_ws, size_t ws_size,
                              hipStream_t stream) {
    const float* vectors      = (const float*)d_in[0];
    const float* node_scalars = (const float*)d_in[1];
    const float* node_vectors = (const float*)d_in[2];
    const float* radial       = (const float*)d_in[3];
    const float* W_up_s       = (const float*)d_in[4];
    const float* W_up_v       = (const float*)d_in[5];
    const float* W1 = (const float*)d_in[6];
    const float* b1 = (const float*)d_in[7];
    const float* W2 = (const float*)d_in[8];
    const float* b2 = (const float*)d_in[9];
    const float* W3 = (const float*)d_in[10];
    const float* b3 = (const float*)d_in[11];
    const float* W4 = (const float*)d_in[12];
    const float* b4 = (const float*)d_in[13];
    const float* Wds  = (const float*)d_in[14];
    const float* Wdv  = (const float*)d_in[15];
    const float* Wz   = (const float*)d_in[16];
    const float* Wsc  = (const float*)d_in[17];
    const float* Wpost= (const float*)d_in[18];
    const float* Wro1 = (const float*)d_in[19];
    const float* Wro2 = (const float*)d_in[20];
    const int* senders   = (const int*)d_in[21];
    const int* receivers = (const int*)d_in[22];
    const int* counts    = (const int*)d_in[23];
    float* out = (float*)d_out;

    const size_t NF = (size_t)N_NODES * F;

    char* base = (char*)d_ws;
    // mix (CSR-ordered, dead after gather) overlays s2/v2/sc16.
    _Float16* mix = (_Float16*)base;                 // E*512 fp16
    float* s2   = (float*)base;                      // N*128 fp32
    float* v2   = s2 + NF;                           // 3N*128 fp32
    _Float16* sc16 = (_Float16*)(v2 + 3 * NF);       // N*128 fp16

    char* p = base + (size_t)N_EDGES * 512 * 2;
    float4* yq     = (float4*)p;          p += (size_t)N_EDGES * 16;
    _Float16* ns16 = (_Float16*)p;        p += NF * 2;
    _Float16* nv16 = (_Float16*)p;        p += 3 * NF * 2;
    _Float16* s16  = (_Float16*)p;        p += NF * 2;
    _Float16* v16  = (_Float16*)p;        p += 3 * NF * 2;
    float* selfc   = (float*)p;           p += NF * 4;
    _Float16* agg_s16 = (_Float16*)p;     p += 2 * NF * 2;
    _Float16* agg_v16 = (_Float16*)p;     p += 6 * NF * 2;
    int* deg    = (int*)p;                p += N_NODES * 4;
    int* offs   = (int*)p;                p += (N_NODES + 1) * 4 + 12;  // pad
    int* cursor = (int*)p;                p += N_NODES * 4;
    _Float16* W2t = (_Float16*)p;         p += 4096 * 2;
    _Float16* W3t = (_Float16*)p;         p += 4096 * 2;
    _Float16* W4t = (_Float16*)p;         p += 32768 * 2;
    float* b4p    = (float*)p;            p += 512 * 4;
    _Float16* Wup_s_t = (_Float16*)p;     p += 16384 * 2;
    _Float16* Wup_v_t = (_Float16*)p;     p += 16384 * 2;
    _Float16* Wz_t    = (_Float16*)p;     p += 65536 * 2;
    _Float16* Wds_t   = (_Float16*)p;     p += 32768 * 2;
    _Float16* Wdv_t   = (_Float16*)p;     p += 32768 * 2;
    _Float16* Wpost_t = (_Float16*)p;     p += 16384 * 2;

    // re_csr (E*8 floats) ALIASES agg_v16: written by k_fill, read by k_mlp;
    // agg_v16 written only by k_gather which runs strictly after k_mlp.
    float4* re_csr = (float4*)agg_v16;

    hipMemsetAsync(deg, 0, N_NODES * sizeof(int), stream);

    k_setup<<<21491, 256, 0, stream>>>(
        receivers, deg, W2, W3, W4, b4, W_up_s, W_up_v, Wz, Wds, Wdv, Wpost,
        W2t, W3t, W4t, b4p, Wup_s_t, Wup_v_t, Wz_t, Wds_t, Wdv_t, Wpost_t,
        node_scalars, node_vectors, ns16, nv16);

    k_scan<<<1, 1024, 0, stream>>>(deg, offs, cursor);

    k_fill<<<(N_EDGES + 255) / 256, 256, 0, stream>>>(
        receivers, senders, vectors, radial, cursor, yq, re_csr);

    k_gemm_up<<<dim3(235, 3), 256, 0, stream>>>(
        ns16, nv16, Wup_s_t, Wup_v_t, Wz_t, counts, s16, v16, selfc);

    k_mlp<<<N_EDGES / TE, 256, 0, stream>>>(
        (const float*)re_csr, W1, b1, W2t, b2, W3t, b3, W4t, b4p, mix);

    k_gather<<<N_NODES, 128, 0, stream>>>(
        mix, yq, s16, v16, offs, agg_s16, agg_v16);

    k_gemm_down<<<dim3(235, 2), 256, 0, stream>>>(
        agg_s16, agg_v16, Wds_t, Wdv_t, counts, s2, v2);

    k_contract<<<(N_NODES * F) / 256, 256, 0, stream>>>(s2, v2, Wsc, counts, sc16);

    k_post<<<(N_NODES + 127) / 128, 256, 0, stream>>>(
        sc16, Wpost_t, selfc, Wro1, Wro2, out);
}

// Round 10
// 315.277 us; speedup vs baseline: 1.1853x; 1.0231x over previous
//
#include <hip/hip_runtime.h>
#include <hip/hip_bf16.h>
#include <math.h>

#define N_NODES 10000
#define N_EDGES 160000
#define F 128
#define TE 128        // edges per block in k_mlp
#define HS 72         // fp16 row stride for h tiles in LDS

typedef _Float16 v8h __attribute__((ext_vector_type(8)));
typedef _Float16 v4h __attribute__((ext_vector_type(4)));
typedef float    v4f __attribute__((ext_vector_type(4)));

__device__ __forceinline__ float nsilu(float x) {
    return 1.679177f * (x / (1.0f + expf(-x)));
}

__device__ __forceinline__ void fma4(float4& a, float s, const float4& b) {
    a.x = fmaf(s, b.x, a.x); a.y = fmaf(s, b.y, a.y);
    a.z = fmaf(s, b.z, a.z); a.w = fmaf(s, b.w, a.w);
}

__device__ __forceinline__ int species_of(int n, const int* __restrict__ counts) {
    int c0 = counts[0];
    int c01 = c0 + counts[1];
    int c012 = c01 + counts[2];
    return (n >= c0) + (n >= c01) + (n >= c012);
}

// ---------------------------------------------------------------------------
// k_setup: fused degree-count + weight prep (fp16 n-major) + input prep.
// ---------------------------------------------------------------------------
__global__ __launch_bounds__(256) void k_setup(
    const int* __restrict__ receivers, int* __restrict__ deg,
    const float* __restrict__ W2, const float* __restrict__ W3,
    const float* __restrict__ W4, const float* __restrict__ b4,
    const float* __restrict__ Wup_s, const float* __restrict__ Wup_v,
    const float* __restrict__ Wz, const float* __restrict__ Wds,
    const float* __restrict__ Wdv, const float* __restrict__ Wpost,
    const float* __restrict__ Wro1,
    _Float16* __restrict__ W2t, _Float16* __restrict__ W3t,
    _Float16* __restrict__ W4t, float* __restrict__ b4p,
    _Float16* __restrict__ Wup_s_t, _Float16* __restrict__ Wup_v_t,
    _Float16* __restrict__ Wz_t, _Float16* __restrict__ Wds_t,
    _Float16* __restrict__ Wdv_t, _Float16* __restrict__ Wpost_t,
    _Float16* __restrict__ Wro1t,
    const float* __restrict__ ns, const float* __restrict__ nv,
    _Float16* __restrict__ ns16, _Float16* __restrict__ nv16)
{
    int gidx = blockIdx.x * 256 + threadIdx.x;
    if (gidx < N_EDGES) {
        atomicAdd(&deg[receivers[gidx]], 1);
        return;
    }
    int idx = gidx - N_EDGES;
    if (idx < 223744) {
        if (idx < 4096) {                            // W2t[u][k]
            int u = idx >> 6, k = idx & 63;
            W2t[idx] = (_Float16)W2[k * 64 + u];
        } else if (idx < 8192) {                     // W3t
            int j = idx - 4096;
            int u = j >> 6, k = j & 63;
            W3t[j] = (_Float16)W3[k * 64 + u];
        } else if (idx < 40960) {                    // W4t[g_new][k], permuted
            int j = idx - 8192;
            int gn = j >> 6, k = j & 63;
            int go = (gn & 3) * 128 + (gn >> 2);
            W4t[j] = (_Float16)W4[k * 512 + go];
        } else if (idx < 41472) {                    // b4p
            int j = idx - 40960;
            int go = (j & 3) * 128 + (j >> 2);
            b4p[j] = b4[go];
        } else if (idx < 57856) {                    // Wup_s_t[g][f]
            int j = idx - 41472;
            int g = j >> 7, f = j & 127;
            Wup_s_t[j] = (_Float16)Wup_s[f * 128 + g];
        } else if (idx < 74240) {                    // Wup_v_t
            int j = idx - 57856;
            int g = j >> 7, f = j & 127;
            Wup_v_t[j] = (_Float16)Wup_v[f * 128 + g];
        } else if (idx < 139776) {                   // Wz_t[s][g][f]
            int j = idx - 74240;
            int s = j >> 14, r = j & 16383;
            int g = r >> 7, f = r & 127;
            Wz_t[j] = (_Float16)Wz[s * 16384 + f * 128 + g];
        } else if (idx < 172544) {                   // Wds_t[g][k], K=256
            int j = idx - 139776;
            int g = j >> 8, k = j & 255;
            Wds_t[j] = (_Float16)Wds[k * 128 + g];
        } else if (idx < 205312) {                   // Wdv_t
            int j = idx - 172544;
            int g = j >> 8, k = j & 255;
            Wdv_t[j] = (_Float16)Wdv[k * 128 + g];
        } else if (idx < 221696) {                   // Wpost_t
            int j = idx - 205312;
            int g = j >> 7, f = j & 127;
            Wpost_t[j] = (_Float16)Wpost[f * 128 + g];
        } else {                                     // Wro1t[u][f]
            int j = idx - 221696;
            int u = j >> 7, f = j & 127;
            Wro1t[j] = (_Float16)Wro1[f * 16 + u];
        }
        return;
    }
    int j = idx - 223744;
    if (j < N_NODES * F) {
        ns16[j] = (_Float16)ns[j];
    } else if (j < 4 * N_NODES * F) {
        int j2 = j - N_NODES * F;                    // < 3N*F
        int row = j2 >> 7, f = j2 & 127;
        int n = row / 3, c = row - n * 3;
        nv16[j2] = (_Float16)nv[((size_t)n * F + f) * 3 + c];
    }
}

__global__ __launch_bounds__(1024) void k_scan(const int* __restrict__ deg,
                                               int* __restrict__ offs,
                                               int* __restrict__ cursor) {
    __shared__ int sums[1024];
    const int t = threadIdx.x;
    const int CH = 10;
    int base = t * CH;
    int local[CH];
    int s = 0;
    #pragma unroll
    for (int j = 0; j < CH; ++j) {
        int v = (base + j < N_NODES) ? deg[base + j] : 0;
        local[j] = s;
        s += v;
    }
    sums[t] = s;
    __syncthreads();
    for (int off = 1; off < 1024; off <<= 1) {
        int v = (t >= off) ? sums[t - off] : 0;
        __syncthreads();
        sums[t] += v;
        __syncthreads();
    }
    int carry = (t == 0) ? 0 : sums[t - 1];
    #pragma unroll
    for (int j = 0; j < CH; ++j) {
        int idx = base + j;
        if (idx < N_NODES) {
            int o = carry + local[j];
            offs[idx] = o;
            cursor[idx] = o;
        }
    }
    if (t == 1023) offs[N_NODES] = sums[1023];
}

// k_fill: CSR-permute edge metadata AND the radial embeddings.
__global__ __launch_bounds__(256) void k_fill(const int* __restrict__ receivers,
                                              const int* __restrict__ senders,
                                              const float* __restrict__ vectors,
                                              const float* __restrict__ radial,
                                              int* __restrict__ cursor,
                                              float4* __restrict__ yq,
                                              float4* __restrict__ re_csr) {
    int e = blockIdx.x * 256 + threadIdx.x;
    if (e < N_EDGES) {
        int pos = atomicAdd(&cursor[receivers[e]], 1);
        float vx = vectors[e * 3 + 0];
        float vy = vectors[e * 3 + 1];
        float vz = vectors[e * 3 + 2];
        float inv = 1.0f / (sqrtf(vx * vx + vy * vy + vz * vz) + 1e-12f);
        float4 y;
        y.x = vx * inv; y.y = vy * inv; y.z = vz * inv;
        y.w = __int_as_float(senders[e]);
        yq[pos] = y;
        const float4* rp = (const float4*)(radial + (size_t)e * 8);
        re_csr[pos * 2]     = rp[0];
        re_csr[pos * 2 + 1] = rp[1];
    }
}

// ---------------------------------------------------------------------------
// Generic 128x128 fp16 MFMA GEMM tile; OT = output element type.
// ---------------------------------------------------------------------------
template <int K, typename OT>
__device__ __forceinline__ void gemm_tile(
    const _Float16* __restrict__ A, const _Float16* __restrict__ Bg,
    OT* __restrict__ out, int M, int row0, float scale,
    _Float16* Bl, const int* __restrict__ counts, int sp)
{
    const int t = threadIdx.x;
    constexpr int KP = K + 8;
    __syncthreads();
    for (int idx = t; idx < 128 * (K / 8); idx += 256) {
        int g = idx / (K / 8), kk = (idx % (K / 8)) * 8;
        *(v8h*)(Bl + g * KP + kk) = *(const v8h*)(Bg + g * K + kk);
    }
    __syncthreads();

    const int lane = t & 63;
    const int w = t >> 6;
    const int c = lane & 15;
    const int q = lane >> 4;

    v4f acc[2][8];
    #pragma unroll
    for (int mi = 0; mi < 2; ++mi)
        #pragma unroll
        for (int nt = 0; nt < 8; ++nt)
            acc[mi][nt] = (v4f){0.f, 0.f, 0.f, 0.f};

    for (int ch = 0; ch < K / 32; ++ch) {
        v8h a[2];
        #pragma unroll
        for (int mi = 0; mi < 2; ++mi) {
            int r = row0 + (2 * w + mi) * 16 + c;
            r = min(r, M - 1);
            a[mi] = *(const v8h*)(A + (size_t)r * K + ch * 32 + q * 8);
        }
        #pragma unroll
        for (int nt = 0; nt < 8; ++nt) {
            v8h b = *(const v8h*)(Bl + (nt * 16 + c) * KP + ch * 32 + q * 8);
            acc[0][nt] = __builtin_amdgcn_mfma_f32_16x16x32_f16(a[0], b, acc[0][nt], 0, 0, 0);
            acc[1][nt] = __builtin_amdgcn_mfma_f32_16x16x32_f16(a[1], b, acc[1][nt], 0, 0, 0);
        }
    }
    #pragma unroll
    for (int mi = 0; mi < 2; ++mi) {
        #pragma unroll
        for (int r = 0; r < 4; ++r) {
            int row = row0 + (2 * w + mi) * 16 + q * 4 + r;
            bool ok = row < M;
            if (ok && sp >= 0) ok = (species_of(row, counts) == sp);
            if (ok) {
                OT* op = out + (size_t)row * 128;
                #pragma unroll
                for (int nt = 0; nt < 8; ++nt)
                    op[nt * 16 + c] = (OT)(acc[mi][nt][r] * scale);
            }
        }
    }
}

// grid (235, 3): y=0 s16 (fp16 out), y=1 v16 (fp16 out, M=3N), y=2 selfc (fp32)
__global__ __launch_bounds__(256) void k_gemm_up(
    const _Float16* __restrict__ ns16, const _Float16* __restrict__ nv16,
    const _Float16* __restrict__ Wup_s_t, const _Float16* __restrict__ Wup_v_t,
    const _Float16* __restrict__ Wz_t, const int* __restrict__ counts,
    _Float16* __restrict__ s16, _Float16* __restrict__ v16,
    float* __restrict__ selfc)
{
    __shared__ _Float16 Bl[128 * 136];
    const int row0 = blockIdx.x * 128;
    const float isf = 0.08838834764831845f;
    if (blockIdx.y == 0) {
        if (row0 >= N_NODES) return;
        gemm_tile<128, _Float16>(ns16, Wup_s_t, s16, N_NODES, row0, isf, Bl, counts, -1);
    } else if (blockIdx.y == 1) {
        gemm_tile<128, _Float16>(nv16, Wup_v_t, v16, 3 * N_NODES, row0, isf, Bl, counts, -1);
    } else {
        if (row0 >= N_NODES) return;
        int sp0 = species_of(row0, counts);
        int sp1 = species_of(min(row0 + 127, N_NODES - 1), counts);
        for (int sp = sp0; sp <= sp1; ++sp)
            gemm_tile<128, float>(ns16, Wz_t + (size_t)sp * 16384, selfc,
                                  N_NODES, row0, isf, Bl, counts, sp);
    }
}

__global__ __launch_bounds__(256) void k_gemm_down(
    const _Float16* __restrict__ agg_s16, const _Float16* __restrict__ agg_v16,
    const _Float16* __restrict__ Wds_t, const _Float16* __restrict__ Wdv_t,
    const int* __restrict__ counts,
    float* __restrict__ s2, float* __restrict__ v2)
{
    __shared__ _Float16 Bl[128 * 264];
    const int row0 = blockIdx.x * 128;
    if (blockIdx.y == 0) {
        if (row0 >= N_NODES) return;
        gemm_tile<256, float>(agg_s16, Wds_t, s2, N_NODES, row0, 1.0f, Bl, counts, -1);
    } else {
        gemm_tile<256, float>(agg_v16, Wdv_t, v2, 3 * N_NODES, row0, 1.0f, Bl, counts, -1);
    }
}

// ---------------------------------------------------------------------------
// Radial MLP via fp16 MFMA. Layers 2/3: round-7 operand order (LDS writeback
// is 2-way-conflict-free). Layer 4: TRANSPOSED (W as A-operand) so each
// lane's 4 acc values are contiguous in mix -> v4h global stores.
// ---------------------------------------------------------------------------
__device__ __forceinline__ void mfma_layer64(
    const _Float16* src, _Float16* dst,
    const _Float16* __restrict__ Wt, const float* __restrict__ b,
    int w, int q, int c)
{
    v8h B[4][2];
    float bias[4];
    #pragma unroll
    for (int nt = 0; nt < 4; ++nt) {
        B[nt][0] = *(const v8h*)(Wt + (nt * 16 + c) * 64 + q * 8);
        B[nt][1] = *(const v8h*)(Wt + (nt * 16 + c) * 64 + 32 + q * 8);
        bias[nt] = b[nt * 16 + c];
    }
    #pragma unroll
    for (int mi = 0; mi < 2; ++mi) {
        int mt = 2 * w + mi;
        v8h a0 = *(const v8h*)(src + (mt * 16 + c) * HS + q * 8);
        v8h a1 = *(const v8h*)(src + (mt * 16 + c) * HS + 32 + q * 8);
        #pragma unroll
        for (int nt = 0; nt < 4; ++nt) {
            v4f acc = {bias[nt], bias[nt], bias[nt], bias[nt]};
            acc = __builtin_amdgcn_mfma_f32_16x16x32_f16(a0, B[nt][0], acc, 0, 0, 0);
            acc = __builtin_amdgcn_mfma_f32_16x16x32_f16(a1, B[nt][1], acc, 0, 0, 0);
            #pragma unroll
            for (int r = 0; r < 4; ++r)
                dst[(mt * 16 + q * 4 + r) * HS + nt * 16 + c] = (_Float16)nsilu(acc[r]);
        }
    }
}

__global__ __launch_bounds__(256) void k_mlp(
    const float* __restrict__ re_csr,
    const float* __restrict__ W1, const float* __restrict__ b1,
    const _Float16* __restrict__ W2t, const float* __restrict__ b2,
    const _Float16* __restrict__ W3t, const float* __restrict__ b3,
    const _Float16* __restrict__ W4t, const float* __restrict__ b4p,
    _Float16* __restrict__ mix)
{
    __shared__ float sre[TE * 8];
    __shared__ _Float16 hA[TE * HS];
    __shared__ _Float16 hB[TE * HS];

    const int t = threadIdx.x;
    const int p0 = blockIdx.x * TE;      // CSR position base

    ((float4*)sre)[t] = ((const float4*)(re_csr + (size_t)p0 * 8))[t];
    __syncthreads();

    {
        const int uslot = t & 15;
        const int egrp = t >> 4;
        const int u0 = uslot * 4;
        float4 w[8];
        #pragma unroll
        for (int k = 0; k < 8; ++k) w[k] = *(const float4*)(W1 + k * 64 + u0);
        float4 bb = *(const float4*)(b1 + u0);
        #pragma unroll
        for (int i = 0; i < 8; ++i) {
            int e = egrp + i * 16;
            const float* rp = sre + e * 8;
            float4 a = bb;
            #pragma unroll
            for (int k = 0; k < 8; ++k) fma4(a, rp[k], w[k]);
            v4h r = {(_Float16)nsilu(a.x), (_Float16)nsilu(a.y),
                     (_Float16)nsilu(a.z), (_Float16)nsilu(a.w)};
            *(v4h*)(hA + e * HS + u0) = r;
        }
    }
    __syncthreads();

    const int lane = t & 63;
    const int w = t >> 6;
    const int c = lane & 15;
    const int q = lane >> 4;

    mfma_layer64(hA, hB, W2t, b2, w, q, c);
    mfma_layer64(hB, hA, W3t, b3, w, q, c);
    __syncthreads();

    // layer 4 (transposed): wave w owns g-tiles [8w, 8w+8)
    v8h A4[8][2];
    v4f bias4[8];
    #pragma unroll
    for (int j = 0; j < 8; ++j) {
        int g0 = (8 * w + j) * 16;
        A4[j][0] = *(const v8h*)(W4t + (g0 + c) * 64 + q * 8);
        A4[j][1] = *(const v8h*)(W4t + (g0 + c) * 64 + 32 + q * 8);
        float4 bb = *(const float4*)(b4p + g0 + q * 4);
        bias4[j] = (v4f){bb.x, bb.y, bb.z, bb.w};
    }
    for (int mt = 0; mt < 8; ++mt) {
        v8h h0 = *(const v8h*)(hA + (mt * 16 + c) * HS + q * 8);
        v8h h1 = *(const v8h*)(hA + (mt * 16 + c) * HS + 32 + q * 8);
        size_t rowbase = (size_t)(p0 + mt * 16 + c) * 512;
        #pragma unroll
        for (int j = 0; j < 8; ++j) {
            v4f acc = bias4[j];
            acc = __builtin_amdgcn_mfma_f32_16x16x32_f16(A4[j][0], h0, acc, 0, 0, 0);
            acc = __builtin_amdgcn_mfma_f32_16x16x32_f16(A4[j][1], h1, acc, 0, 0, 0);
            v4h r = {(_Float16)acc[0], (_Float16)acc[1],
                     (_Float16)acc[2], (_Float16)acc[3]};
            *(v4h*)(mix + rowbase + (8 * w + j) * 16 + q * 4) = r;
        }
    }
}

// ---------------------------------------------------------------------------
// Gather: mix CSR-ordered (sequential). yq chunk-prefetched into LDS.
// ---------------------------------------------------------------------------
__global__ __launch_bounds__(128) void k_gather(
    const _Float16* __restrict__ mix, const float4* __restrict__ yq,
    const _Float16* __restrict__ s16, const _Float16* __restrict__ v16,
    const int* __restrict__ offs,
    _Float16* __restrict__ agg_s16, _Float16* __restrict__ agg_v16)
{
    const int n = blockIdx.x;
    const int f = threadIdx.x;
    const int beg = offs[n], end = offs[n + 1];
    const float inv_sqrt3 = 0.5773502691896258f;
    __shared__ float4 ly[32];

    float as0 = 0, as1 = 0;
    float av00 = 0, av01 = 0, av02 = 0, av10 = 0, av11 = 0, av12 = 0;

    for (int c0 = beg; c0 < end; c0 += 32) {
        int cnt = min(32, end - c0);
        __syncthreads();
        if (f < cnt) ly[f] = yq[c0 + f];
        __syncthreads();
        #pragma unroll 4
        for (int i = 0; i < cnt; ++i) {
            float4 y = ly[i];
            int snd = __float_as_int(y.w);

            union { uint2 u; _Float16 h[4]; } mu;
            mu.u = *(const uint2*)(mix + (size_t)(c0 + i) * 512 + f * 4);
            float m0 = (float)mu.h[0];
            float m1 = (float)mu.h[1];
            float m2 = (float)mu.h[2];
            float m3 = (float)mu.h[3];

            float sg = (float)s16[(size_t)snd * F + f];
            const _Float16* vb = v16 + (size_t)snd * 384;
            float vg0 = (float)vb[f];
            float vg1 = (float)vb[128 + f];
            float vg2 = (float)vb[256 + f];

            as0 += m0 * sg;
            as1 += m3 * (vg0 * y.x + vg1 * y.y + vg2 * y.z) * inv_sqrt3;
            float w1s = m1 * sg;
            av00 += w1s * y.x; av01 += w1s * y.y; av02 += w1s * y.z;
            av10 += m2 * vg0;  av11 += m2 * vg1;  av12 += m2 * vg2;
        }
    }
    const float SC = 0.011048543456039804f;          // EPS / sqrt(256)
    agg_s16[(size_t)n * 256 + f]       = (_Float16)(as0 * SC);
    agg_s16[(size_t)n * 256 + 128 + f] = (_Float16)(as1 * SC);
    _Float16* av = agg_v16 + (size_t)n * 768;
    av[0 * 256 + f]       = (_Float16)(av00 * SC);
    av[0 * 256 + 128 + f] = (_Float16)(av10 * SC);
    av[1 * 256 + f]       = (_Float16)(av01 * SC);
    av[1 * 256 + 128 + f] = (_Float16)(av11 * SC);
    av[2 * 256 + f]       = (_Float16)(av02 * SC);
    av[2 * 256 + 128 + f] = (_Float16)(av12 * SC);
}

// ---------------------------------------------------------------------------
// k_post: fused symmetric contraction + post GEMM + MFMA readout.
// ---------------------------------------------------------------------------
__global__ __launch_bounds__(256) void k_post(
    const float* __restrict__ s2, const float* __restrict__ v2,
    const float* __restrict__ Wsc, const int* __restrict__ counts,
    const _Float16* __restrict__ Wpost_t, const float* __restrict__ selfc,
    const _Float16* __restrict__ Wro1t, const float* __restrict__ Wro2,
    float* __restrict__ out)
{
    __shared__ _Float16 Bl[128 * 136];
    __shared__ _Float16 Al[128 * 136];   // sc16, then reused as sfeat16
    __shared__ float shr[128 * 16];
    const int t = threadIdx.x;
    const int row0 = blockIdx.x * 128;
    const float isf = 0.08838834764831845f;

    for (int idx = t; idx < 128 * 16; idx += 256) {
        int g = idx >> 4, kk = (idx & 15) * 8;
        *(v8h*)(Bl + g * 136 + kk) = *(const v8h*)(Wpost_t + g * 128 + kk);
    }

    // fused contract -> Al fp16 (A operand of post GEMM)
    #pragma unroll 4
    for (int i = 0; i < 16; ++i) {
        int idx = t + i * 256;           // r*32 + c4
        int r = idx >> 5, c4 = idx & 31;
        int rc = min(row0 + r, N_NODES - 1);
        float4 s4 = *(const float4*)(s2 + (size_t)rc * 128 + c4 * 4);
        float4 a0 = *(const float4*)(v2 + ((size_t)rc * 3 + 0) * 128 + c4 * 4);
        float4 a1 = *(const float4*)(v2 + ((size_t)rc * 3 + 1) * 128 + c4 * 4);
        float4 a2 = *(const float4*)(v2 + ((size_t)rc * 3 + 2) * 128 + c4 * 4);
        const float* w = Wsc + (size_t)species_of(rc, counts) * 640 + c4 * 4;
        float4 w0 = *(const float4*)(w);
        float4 w1 = *(const float4*)(w + 128);
        float4 w2 = *(const float4*)(w + 256);
        float4 w3 = *(const float4*)(w + 384);
        float4 w4 = *(const float4*)(w + 512);
        v4h r16;
        {
            float s = s4.x, vv = a0.x*a0.x + a1.x*a1.x + a2.x*a2.x;
            r16[0] = (_Float16)(w0.x*s + w1.x*(s*s) + w2.x*vv + w3.x*(s*s*s) + w4.x*(s*vv));
        }
        {
            float s = s4.y, vv = a0.y*a0.y + a1.y*a1.y + a2.y*a2.y;
            r16[1] = (_Float16)(w0.y*s + w1.y*(s*s) + w2.y*vv + w3.y*(s*s*s) + w4.y*(s*vv));
        }
        {
            float s = s4.z, vv = a0.z*a0.z + a1.z*a1.z + a2.z*a2.z;
            r16[2] = (_Float16)(w0.z*s + w1.z*(s*s) + w2.z*vv + w3.z*(s*s*s) + w4.z*(s*vv));
        }
        {
            float s = s4.w, vv = a0.w*a0.w + a1.w*a1.w + a2.w*a2.w;
            r16[3] = (_Float16)(w0.w*s + w1.w*(s*s) + w2.w*vv + w3.w*(s*s*s) + w4.w*(s*vv));
        }
        *(v4h*)(Al + r * 136 + c4 * 4) = r16;
    }
    __syncthreads();

    const int lane = t & 63;
    const int w = t >> 6;
    const int c = lane & 15;
    const int q = lane >> 4;

    // post GEMM: feats-pre = Al @ Wpost_t
    v4f acc[2][8];
    #pragma unroll
    for (int mi = 0; mi < 2; ++mi)
        #pragma unroll
        for (int nt = 0; nt < 8; ++nt)
            acc[mi][nt] = (v4f){0.f, 0.f, 0.f, 0.f};

    for (int ch = 0; ch < 4; ++ch) {
        v8h a[2];
        #pragma unroll
        for (int mi = 0; mi < 2; ++mi)
            a[mi] = *(const v8h*)(Al + ((2 * w + mi) * 16 + c) * 136 + ch * 32 + q * 8);
        #pragma unroll
        for (int nt = 0; nt < 8; ++nt) {
            v8h b = *(const v8h*)(Bl + (nt * 16 + c) * 136 + ch * 32 + q * 8);
            acc[0][nt] = __builtin_amdgcn_mfma_f32_16x16x32_f16(a[0], b, acc[0][nt], 0, 0, 0);
            acc[1][nt] = __builtin_amdgcn_mfma_f32_16x16x32_f16(a[1], b, acc[1][nt], 0, 0, 0);
        }
    }
    __syncthreads();                     // all waves done reading Al

    // epilogue: feats -> out + Al (fp16, for readout)
    #pragma unroll
    for (int mi = 0; mi < 2; ++mi) {
        #pragma unroll
        for (int r = 0; r < 4; ++r) {
            int row = row0 + (2 * w + mi) * 16 + q * 4 + r;
            int rl = (2 * w + mi) * 16 + q * 4 + r;
            if (row < N_NODES) {
                #pragma unroll
                for (int nt = 0; nt < 8; ++nt) {
                    int col = nt * 16 + c;
                    float feat = acc[mi][nt][r] * isf + selfc[(size_t)row * 128 + col];
                    out[N_NODES + (size_t)row * 128 + col] = feat;
                    Al[rl * 136 + col] = (_Float16)feat;
                }
            } else {
                #pragma unroll
                for (int nt = 0; nt < 8; ++nt) Al[rl * 136 + nt * 16 + c] = (_Float16)0.f;
            }
        }
    }
    __syncthreads();

    // readout GEMM: hr = feats @ Wro1t  (M=128, N=16, K=128)
    v4f hacc[2];
    hacc[0] = (v4f){0.f, 0.f, 0.f, 0.f};
    hacc[1] = (v4f){0.f, 0.f, 0.f, 0.f};
    for (int ch = 0; ch < 4; ++ch) {
        v8h b = *(const v8h*)(Wro1t + c * 128 + ch * 32 + q * 8);
        #pragma unroll
        for (int mi = 0; mi < 2; ++mi) {
            v8h a = *(const v8h*)(Al + ((2 * w + mi) * 16 + c) * 136 + ch * 32 + q * 8);
            hacc[mi] = __builtin_amdgcn_mfma_f32_16x16x32_f16(a, b, hacc[mi], 0, 0, 0);
        }
    }
    #pragma unroll
    for (int mi = 0; mi < 2; ++mi)
        #pragma unroll
        for (int r = 0; r < 4; ++r) {
            int rl = (2 * w + mi) * 16 + q * 4 + r;
            shr[rl * 16 + c] = nsilu(hacc[mi][r] * isf);
        }
    __syncthreads();

    if (t < 128 && row0 + t < N_NODES) {
        float a = 0;
        #pragma unroll
        for (int j = 0; j < 16; ++j) a += shr[t * 16 + j] * Wro2[j];
        out[row0 + t] = a * 0.25f;       // 1/sqrt(16)
    }
}

// ---------------------------------------------------------------------------

extern "C" void kernel_launch(void* const* d_in, const int* in_sizes, int n_in,
                              void* d_out, int out_size, void* d_ws, size_t ws_size,
                              hipStream_t stream) {
    const float* vectors      = (const float*)d_in[0];
    const float* node_scalars = (const float*)d_in[1];
    const float* node_vectors = (const float*)d_in[2];
    const float* radial       = (const float*)d_in[3];
    const float* W_up_s       = (const float*)d_in[4];
    const float* W_up_v       = (const float*)d_in[5];
    const float* W1 = (const float*)d_in[6];
    const float* b1 = (const float*)d_in[7];
    const float* W2 = (const float*)d_in[8];
    const float* b2 = (const float*)d_in[9];
    const float* W3 = (const float*)d_in[10];
    const float* b3 = (const float*)d_in[11];
    const float* W4 = (const float*)d_in[12];
    const float* b4 = (const float*)d_in[13];
    const float* Wds  = (const float*)d_in[14];
    const float* Wdv  = (const float*)d_in[15];
    const float* Wz   = (const float*)d_in[16];
    const float* Wsc  = (const float*)d_in[17];
    const float* Wpost= (const float*)d_in[18];
    const float* Wro1 = (const float*)d_in[19];
    const float* Wro2 = (const float*)d_in[20];
    const int* senders   = (const int*)d_in[21];
    const int* receivers = (const int*)d_in[22];
    const int* counts    = (const int*)d_in[23];
    float* out = (float*)d_out;

    const size_t NF = (size_t)N_NODES * F;

    char* base = (char*)d_ws;
    // mix (CSR-ordered, dead after gather) overlays s2/v2.
    _Float16* mix = (_Float16*)base;                 // E*512 fp16
    float* s2   = (float*)base;                      // N*128 fp32
    float* v2   = s2 + NF;                           // 3N*128 fp32

    char* p = base + (size_t)N_EDGES * 512 * 2;
    float4* yq     = (float4*)p;          p += (size_t)N_EDGES * 16;
    _Float16* ns16 = (_Float16*)p;        p += NF * 2;
    _Float16* nv16 = (_Float16*)p;        p += 3 * NF * 2;
    _Float16* s16  = (_Float16*)p;        p += NF * 2;
    _Float16* v16  = (_Float16*)p;        p += 3 * NF * 2;
    float* selfc   = (float*)p;           p += NF * 4;
    _Float16* agg_s16 = (_Float16*)p;     p += 2 * NF * 2;
    _Float16* agg_v16 = (_Float16*)p;     p += 6 * NF * 2;
    int* deg    = (int*)p;                p += N_NODES * 4;
    int* offs   = (int*)p;                p += (N_NODES + 1) * 4 + 12;  // pad
    int* cursor = (int*)p;                p += N_NODES * 4;
    _Float16* W2t = (_Float16*)p;         p += 4096 * 2;
    _Float16* W3t = (_Float16*)p;         p += 4096 * 2;
    _Float16* W4t = (_Float16*)p;         p += 32768 * 2;
    float* b4p    = (float*)p;            p += 512 * 4;
    _Float16* Wup_s_t = (_Float16*)p;     p += 16384 * 2;
    _Float16* Wup_v_t = (_Float16*)p;     p += 16384 * 2;
    _Float16* Wz_t    = (_Float16*)p;     p += 65536 * 2;
    _Float16* Wds_t   = (_Float16*)p;     p += 32768 * 2;
    _Float16* Wdv_t   = (_Float16*)p;     p += 32768 * 2;
    _Float16* Wpost_t = (_Float16*)p;     p += 16384 * 2;
    _Float16* Wro1t   = (_Float16*)p;     p += 2048 * 2;

    // re_csr (E*8 floats) ALIASES agg_v16: written by k_fill, read by k_mlp;
    // agg_v16 written only by k_gather which runs strictly after k_mlp.
    float4* re_csr = (float4*)agg_v16;

    hipMemsetAsync(deg, 0, N_NODES * sizeof(int), stream);

    k_setup<<<21499, 256, 0, stream>>>(
        receivers, deg, W2, W3, W4, b4, W_up_s, W_up_v, Wz, Wds, Wdv, Wpost, Wro1,
        W2t, W3t, W4t, b4p, Wup_s_t, Wup_v_t, Wz_t, Wds_t, Wdv_t, Wpost_t, Wro1t,
        node_scalars, node_vectors, ns16, nv16);

    k_scan<<<1, 1024, 0, stream>>>(deg, offs, cursor);

    k_fill<<<(N_EDGES + 255) / 256, 256, 0, stream>>>(
        receivers, senders, vectors, radial, cursor, yq, re_csr);

    k_gemm_up<<<dim3(235, 3), 256, 0, stream>>>(
        ns16, nv16, Wup_s_t, Wup_v_t, Wz_t, counts, s16, v16, selfc);

    k_mlp<<<N_EDGES / TE, 256, 0, stream>>>(
        (const float*)re_csr, W1, b1, W2t, b2, W3t, b3, W4t, b4p, mix);

    k_gather<<<N_NODES, 128, 0, stream>>>(
        mix, yq, s16, v16, offs, agg_s16, agg_v16);

    k_gemm_down<<<dim3(235, 2), 256, 0, stream>>>(
        agg_s16, agg_v16, Wds_t, Wdv_t, counts, s2, v2);

    k_post<<<(N_NODES + 127) / 128, 256, 0, stream>>>(
        s2, v2, Wsc, counts, Wpost_t, selfc, Wro1t, Wro2, out);
}

// Round 11
// 296.208 us; speedup vs baseline: 1.2616x; 1.0644x over previous
//
#include <hip/hip_runtime.h>
#include <hip/hip_bf16.h>
#include <math.h>

#define N_NODES 10000
#define N_EDGES 160000
#define F 128
#define TE 128        // edges per block in k_mlp
#define HS 72         // fp16 row stride for h tiles in LDS

typedef _Float16 v8h __attribute__((ext_vector_type(8)));
typedef _Float16 v4h __attribute__((ext_vector_type(4)));
typedef float    v4f __attribute__((ext_vector_type(4)));

__device__ __forceinline__ float nsilu(float x) {
    return 1.679177f * (x / (1.0f + expf(-x)));
}

__device__ __forceinline__ void fma4(float4& a, float s, const float4& b) {
    a.x = fmaf(s, b.x, a.x); a.y = fmaf(s, b.y, a.y);
    a.z = fmaf(s, b.z, a.z); a.w = fmaf(s, b.w, a.w);
}

__device__ __forceinline__ int species_of(int n, const int* __restrict__ counts) {
    int c0 = counts[0];
    int c01 = c0 + counts[1];
    int c012 = c01 + counts[2];
    return (n >= c0) + (n >= c01) + (n >= c012);
}

// ---------------------------------------------------------------------------
// k_setup: fused degree-count + weight prep (fp16 n-major) + input prep.
// ---------------------------------------------------------------------------
__global__ __launch_bounds__(256) void k_setup(
    const int* __restrict__ receivers, int* __restrict__ deg,
    const float* __restrict__ W2, const float* __restrict__ W3,
    const float* __restrict__ W4, const float* __restrict__ b4,
    const float* __restrict__ Wup_s, const float* __restrict__ Wup_v,
    const float* __restrict__ Wz, const float* __restrict__ Wds,
    const float* __restrict__ Wdv, const float* __restrict__ Wpost,
    const float* __restrict__ Wro1,
    _Float16* __restrict__ W2t, _Float16* __restrict__ W3t,
    _Float16* __restrict__ W4t, float* __restrict__ b4p,
    _Float16* __restrict__ Wup_s_t, _Float16* __restrict__ Wup_v_t,
    _Float16* __restrict__ Wz_t, _Float16* __restrict__ Wds_t,
    _Float16* __restrict__ Wdv_t, _Float16* __restrict__ Wpost_t,
    _Float16* __restrict__ Wro1t,
    const float* __restrict__ ns, const float* __restrict__ nv,
    _Float16* __restrict__ ns16, _Float16* __restrict__ nv16)
{
    int gidx = blockIdx.x * 256 + threadIdx.x;
    if (gidx < N_EDGES) {
        atomicAdd(&deg[receivers[gidx]], 1);
        return;
    }
    int idx = gidx - N_EDGES;
    if (idx < 223744) {
        if (idx < 4096) {                            // W2t[u][k]
            int u = idx >> 6, k = idx & 63;
            W2t[idx] = (_Float16)W2[k * 64 + u];
        } else if (idx < 8192) {                     // W3t
            int j = idx - 4096;
            int u = j >> 6, k = j & 63;
            W3t[j] = (_Float16)W3[k * 64 + u];
        } else if (idx < 40960) {                    // W4t[g_new][k], permuted
            int j = idx - 8192;
            int gn = j >> 6, k = j & 63;
            int go = (gn & 3) * 128 + (gn >> 2);
            W4t[j] = (_Float16)W4[k * 512 + go];
        } else if (idx < 41472) {                    // b4p
            int j = idx - 40960;
            int go = (j & 3) * 128 + (j >> 2);
            b4p[j] = b4[go];
        } else if (idx < 57856) {                    // Wup_s_t[g][f]
            int j = idx - 41472;
            int g = j >> 7, f = j & 127;
            Wup_s_t[j] = (_Float16)Wup_s[f * 128 + g];
        } else if (idx < 74240) {                    // Wup_v_t
            int j = idx - 57856;
            int g = j >> 7, f = j & 127;
            Wup_v_t[j] = (_Float16)Wup_v[f * 128 + g];
        } else if (idx < 139776) {                   // Wz_t[s][g][f]
            int j = idx - 74240;
            int s = j >> 14, r = j & 16383;
            int g = r >> 7, f = r & 127;
            Wz_t[j] = (_Float16)Wz[s * 16384 + f * 128 + g];
        } else if (idx < 172544) {                   // Wds_t[g][k], K=256
            int j = idx - 139776;
            int g = j >> 8, k = j & 255;
            Wds_t[j] = (_Float16)Wds[k * 128 + g];
        } else if (idx < 205312) {                   // Wdv_t
            int j = idx - 172544;
            int g = j >> 8, k = j & 255;
            Wdv_t[j] = (_Float16)Wdv[k * 128 + g];
        } else if (idx < 221696) {                   // Wpost_t
            int j = idx - 205312;
            int g = j >> 7, f = j & 127;
            Wpost_t[j] = (_Float16)Wpost[f * 128 + g];
        } else {                                     // Wro1t[u][f]
            int j = idx - 221696;
            int u = j >> 7, f = j & 127;
            Wro1t[j] = (_Float16)Wro1[f * 16 + u];
        }
        return;
    }
    int j = idx - 223744;
    if (j < N_NODES * F) {
        ns16[j] = (_Float16)ns[j];
    } else if (j < 4 * N_NODES * F) {
        int j2 = j - N_NODES * F;                    // < 3N*F
        int row = j2 >> 7, f = j2 & 127;
        int n = row / 3, c = row - n * 3;
        nv16[j2] = (_Float16)nv[((size_t)n * F + f) * 3 + c];
    }
}

__global__ __launch_bounds__(1024) void k_scan(const int* __restrict__ deg,
                                               int* __restrict__ offs,
                                               int* __restrict__ cursor) {
    __shared__ int sums[1024];
    const int t = threadIdx.x;
    const int CH = 10;
    int base = t * CH;
    int local[CH];
    int s = 0;
    #pragma unroll
    for (int j = 0; j < CH; ++j) {
        int v = (base + j < N_NODES) ? deg[base + j] : 0;
        local[j] = s;
        s += v;
    }
    sums[t] = s;
    __syncthreads();
    for (int off = 1; off < 1024; off <<= 1) {
        int v = (t >= off) ? sums[t - off] : 0;
        __syncthreads();
        sums[t] += v;
        __syncthreads();
    }
    int carry = (t == 0) ? 0 : sums[t - 1];
    #pragma unroll
    for (int j = 0; j < CH; ++j) {
        int idx = base + j;
        if (idx < N_NODES) {
            int o = carry + local[j];
            offs[idx] = o;
            cursor[idx] = o;
        }
    }
    if (t == 1023) offs[N_NODES] = sums[1023];
}

// k_fill: CSR-permute edge metadata AND the radial embeddings.
__global__ __launch_bounds__(256) void k_fill(const int* __restrict__ receivers,
                                              const int* __restrict__ senders,
                                              const float* __restrict__ vectors,
                                              const float* __restrict__ radial,
                                              int* __restrict__ cursor,
                                              float4* __restrict__ yq,
                                              float4* __restrict__ re_csr) {
    int e = blockIdx.x * 256 + threadIdx.x;
    if (e < N_EDGES) {
        int pos = atomicAdd(&cursor[receivers[e]], 1);
        float vx = vectors[e * 3 + 0];
        float vy = vectors[e * 3 + 1];
        float vz = vectors[e * 3 + 2];
        float inv = 1.0f / (sqrtf(vx * vx + vy * vy + vz * vz) + 1e-12f);
        float4 y;
        y.x = vx * inv; y.y = vy * inv; y.z = vz * inv;
        y.w = __int_as_float(senders[e]);
        yq[pos] = y;
        const float4* rp = (const float4*)(radial + (size_t)e * 8);
        re_csr[pos * 2]     = rp[0];
        re_csr[pos * 2 + 1] = rp[1];
    }
}

// ---------------------------------------------------------------------------
// Generic 128x128 fp16 MFMA GEMM tile; OT = output element type.
// ---------------------------------------------------------------------------
template <int K, typename OT>
__device__ __forceinline__ void gemm_tile(
    const _Float16* __restrict__ A, const _Float16* __restrict__ Bg,
    OT* __restrict__ out, int M, int row0, float scale,
    _Float16* Bl, const int* __restrict__ counts, int sp)
{
    const int t = threadIdx.x;
    constexpr int KP = K + 8;
    __syncthreads();
    for (int idx = t; idx < 128 * (K / 8); idx += 256) {
        int g = idx / (K / 8), kk = (idx % (K / 8)) * 8;
        *(v8h*)(Bl + g * KP + kk) = *(const v8h*)(Bg + g * K + kk);
    }
    __syncthreads();

    const int lane = t & 63;
    const int w = t >> 6;
    const int c = lane & 15;
    const int q = lane >> 4;

    v4f acc[2][8];
    #pragma unroll
    for (int mi = 0; mi < 2; ++mi)
        #pragma unroll
        for (int nt = 0; nt < 8; ++nt)
            acc[mi][nt] = (v4f){0.f, 0.f, 0.f, 0.f};

    for (int ch = 0; ch < K / 32; ++ch) {
        v8h a[2];
        #pragma unroll
        for (int mi = 0; mi < 2; ++mi) {
            int r = row0 + (2 * w + mi) * 16 + c;
            r = min(r, M - 1);
            a[mi] = *(const v8h*)(A + (size_t)r * K + ch * 32 + q * 8);
        }
        #pragma unroll
        for (int nt = 0; nt < 8; ++nt) {
            v8h b = *(const v8h*)(Bl + (nt * 16 + c) * KP + ch * 32 + q * 8);
            acc[0][nt] = __builtin_amdgcn_mfma_f32_16x16x32_f16(a[0], b, acc[0][nt], 0, 0, 0);
            acc[1][nt] = __builtin_amdgcn_mfma_f32_16x16x32_f16(a[1], b, acc[1][nt], 0, 0, 0);
        }
    }
    #pragma unroll
    for (int mi = 0; mi < 2; ++mi) {
        #pragma unroll
        for (int r = 0; r < 4; ++r) {
            int row = row0 + (2 * w + mi) * 16 + q * 4 + r;
            bool ok = row < M;
            if (ok && sp >= 0) ok = (species_of(row, counts) == sp);
            if (ok) {
                OT* op = out + (size_t)row * 128;
                #pragma unroll
                for (int nt = 0; nt < 8; ++nt)
                    op[nt * 16 + c] = (OT)(acc[mi][nt][r] * scale);
            }
        }
    }
}

// grid (235, 3): y=0 s16 (fp16 out), y=1 v16 (fp16 out, M=3N), y=2 selfc (fp32)
__global__ __launch_bounds__(256) void k_gemm_up(
    const _Float16* __restrict__ ns16, const _Float16* __restrict__ nv16,
    const _Float16* __restrict__ Wup_s_t, const _Float16* __restrict__ Wup_v_t,
    const _Float16* __restrict__ Wz_t, const int* __restrict__ counts,
    _Float16* __restrict__ s16, _Float16* __restrict__ v16,
    float* __restrict__ selfc)
{
    __shared__ _Float16 Bl[128 * 136];
    const int row0 = blockIdx.x * 128;
    const float isf = 0.08838834764831845f;
    if (blockIdx.y == 0) {
        if (row0 >= N_NODES) return;
        gemm_tile<128, _Float16>(ns16, Wup_s_t, s16, N_NODES, row0, isf, Bl, counts, -1);
    } else if (blockIdx.y == 1) {
        gemm_tile<128, _Float16>(nv16, Wup_v_t, v16, 3 * N_NODES, row0, isf, Bl, counts, -1);
    } else {
        if (row0 >= N_NODES) return;
        int sp0 = species_of(row0, counts);
        int sp1 = species_of(min(row0 + 127, N_NODES - 1), counts);
        for (int sp = sp0; sp <= sp1; ++sp)
            gemm_tile<128, float>(ns16, Wz_t + (size_t)sp * 16384, selfc,
                                  N_NODES, row0, isf, Bl, counts, sp);
    }
}

__global__ __launch_bounds__(256) void k_gemm_down(
    const _Float16* __restrict__ agg_s16, const _Float16* __restrict__ agg_v16,
    const _Float16* __restrict__ Wds_t, const _Float16* __restrict__ Wdv_t,
    const int* __restrict__ counts,
    float* __restrict__ s2, float* __restrict__ v2)
{
    __shared__ _Float16 Bl[128 * 264];
    const int row0 = blockIdx.x * 128;
    if (blockIdx.y == 0) {
        if (row0 >= N_NODES) return;
        gemm_tile<256, float>(agg_s16, Wds_t, s2, N_NODES, row0, 1.0f, Bl, counts, -1);
    } else {
        gemm_tile<256, float>(agg_v16, Wdv_t, v2, 3 * N_NODES, row0, 1.0f, Bl, counts, -1);
    }
}

// ---------------------------------------------------------------------------
// Radial MLP via fp16 MFMA — round-7 structure exactly (known 58 µs), plus
// sre overlaid on hB (sre dead after layer 1; barrier separates) -> 36.9 KB
// LDS -> 4 blocks/CU instead of 3.
// ---------------------------------------------------------------------------
__device__ __forceinline__ void mfma_layer64(
    const _Float16* src, _Float16* dst,
    const _Float16* __restrict__ Wt, const float* __restrict__ b,
    int w, int q, int c)
{
    v8h B[4][2];
    float bias[4];
    #pragma unroll
    for (int nt = 0; nt < 4; ++nt) {
        B[nt][0] = *(const v8h*)(Wt + (nt * 16 + c) * 64 + q * 8);
        B[nt][1] = *(const v8h*)(Wt + (nt * 16 + c) * 64 + 32 + q * 8);
        bias[nt] = b[nt * 16 + c];
    }
    #pragma unroll
    for (int mi = 0; mi < 2; ++mi) {
        int mt = 2 * w + mi;
        v8h a0 = *(const v8h*)(src + (mt * 16 + c) * HS + q * 8);
        v8h a1 = *(const v8h*)(src + (mt * 16 + c) * HS + 32 + q * 8);
        #pragma unroll
        for (int nt = 0; nt < 4; ++nt) {
            v4f acc = {bias[nt], bias[nt], bias[nt], bias[nt]};
            acc = __builtin_amdgcn_mfma_f32_16x16x32_f16(a0, B[nt][0], acc, 0, 0, 0);
            acc = __builtin_amdgcn_mfma_f32_16x16x32_f16(a1, B[nt][1], acc, 0, 0, 0);
            #pragma unroll
            for (int r = 0; r < 4; ++r)
                dst[(mt * 16 + q * 4 + r) * HS + nt * 16 + c] = (_Float16)nsilu(acc[r]);
        }
    }
}

__global__ __launch_bounds__(256) void k_mlp(
    const float* __restrict__ re_csr,
    const float* __restrict__ W1, const float* __restrict__ b1,
    const _Float16* __restrict__ W2t, const float* __restrict__ b2,
    const _Float16* __restrict__ W3t, const float* __restrict__ b3,
    const _Float16* __restrict__ W4t, const float* __restrict__ b4p,
    _Float16* __restrict__ mix)
{
    __shared__ _Float16 hA[TE * HS];
    __shared__ _Float16 hB[TE * HS];
    float* sre = (float*)hB;             // overlay: sre dead before hB written

    const int t = threadIdx.x;
    const int p0 = blockIdx.x * TE;      // CSR position base

    ((float4*)sre)[t] = ((const float4*)(re_csr + (size_t)p0 * 8))[t];
    __syncthreads();

    {
        const int uslot = t & 15;
        const int egrp = t >> 4;
        const int u0 = uslot * 4;
        float4 w[8];
        #pragma unroll
        for (int k = 0; k < 8; ++k) w[k] = *(const float4*)(W1 + k * 64 + u0);
        float4 bb = *(const float4*)(b1 + u0);
        #pragma unroll
        for (int i = 0; i < 8; ++i) {
            int e = egrp + i * 16;
            const float* rp = sre + e * 8;
            float4 a = bb;
            #pragma unroll
            for (int k = 0; k < 8; ++k) fma4(a, rp[k], w[k]);
            v4h r = {(_Float16)nsilu(a.x), (_Float16)nsilu(a.y),
                     (_Float16)nsilu(a.z), (_Float16)nsilu(a.w)};
            *(v4h*)(hA + e * HS + u0) = r;
        }
    }
    __syncthreads();                     // last sre read before hB write

    const int lane = t & 63;
    const int w = t >> 6;
    const int c = lane & 15;
    const int q = lane >> 4;

    mfma_layer64(hA, hB, W2t, b2, w, q, c);
    mfma_layer64(hB, hA, W3t, b3, w, q, c);
    __syncthreads();

    // layer 4: wave w owns n-tiles [8w, 8w+8)  (round-7 store path)
    v8h B4[8][2];
    float bias4[8];
    #pragma unroll
    for (int j = 0; j < 8; ++j) {
        int g = (8 * w + j) * 16 + c;
        B4[j][0] = *(const v8h*)(W4t + g * 64 + q * 8);
        B4[j][1] = *(const v8h*)(W4t + g * 64 + 32 + q * 8);
        bias4[j] = b4p[g];
    }
    for (int mt = 0; mt < 8; ++mt) {
        v8h a0 = *(const v8h*)(hA + (mt * 16 + c) * HS + q * 8);
        v8h a1 = *(const v8h*)(hA + (mt * 16 + c) * HS + 32 + q * 8);
        size_t rowbase = (size_t)(p0 + mt * 16 + q * 4) * 512;
        #pragma unroll
        for (int j = 0; j < 8; ++j) {
            v4f acc = {bias4[j], bias4[j], bias4[j], bias4[j]};
            acc = __builtin_amdgcn_mfma_f32_16x16x32_f16(a0, B4[j][0], acc, 0, 0, 0);
            acc = __builtin_amdgcn_mfma_f32_16x16x32_f16(a1, B4[j][1], acc, 0, 0, 0);
            int gcol = (8 * w + j) * 16 + c;
            #pragma unroll
            for (int r = 0; r < 4; ++r)
                mix[rowbase + (size_t)r * 512 + gcol] = (_Float16)acc[r];
        }
    }
}

// ---------------------------------------------------------------------------
// Gather: mix CSR-ordered (sequential). yq chunk-prefetched into LDS.
// ---------------------------------------------------------------------------
__global__ __launch_bounds__(128) void k_gather(
    const _Float16* __restrict__ mix, const float4* __restrict__ yq,
    const _Float16* __restrict__ s16, const _Float16* __restrict__ v16,
    const int* __restrict__ offs,
    _Float16* __restrict__ agg_s16, _Float16* __restrict__ agg_v16)
{
    const int n = blockIdx.x;
    const int f = threadIdx.x;
    const int beg = offs[n], end = offs[n + 1];
    const float inv_sqrt3 = 0.5773502691896258f;
    __shared__ float4 ly[32];

    float as0 = 0, as1 = 0;
    float av00 = 0, av01 = 0, av02 = 0, av10 = 0, av11 = 0, av12 = 0;

    for (int c0 = beg; c0 < end; c0 += 32) {
        int cnt = min(32, end - c0);
        __syncthreads();
        if (f < cnt) ly[f] = yq[c0 + f];
        __syncthreads();
        #pragma unroll 4
        for (int i = 0; i < cnt; ++i) {
            float4 y = ly[i];
            int snd = __float_as_int(y.w);

            union { uint2 u; _Float16 h[4]; } mu;
            mu.u = *(const uint2*)(mix + (size_t)(c0 + i) * 512 + f * 4);
            float m0 = (float)mu.h[0];
            float m1 = (float)mu.h[1];
            float m2 = (float)mu.h[2];
            float m3 = (float)mu.h[3];

            float sg = (float)s16[(size_t)snd * F + f];
            const _Float16* vb = v16 + (size_t)snd * 384;
            float vg0 = (float)vb[f];
            float vg1 = (float)vb[128 + f];
            float vg2 = (float)vb[256 + f];

            as0 += m0 * sg;
            as1 += m3 * (vg0 * y.x + vg1 * y.y + vg2 * y.z) * inv_sqrt3;
            float w1s = m1 * sg;
            av00 += w1s * y.x; av01 += w1s * y.y; av02 += w1s * y.z;
            av10 += m2 * vg0;  av11 += m2 * vg1;  av12 += m2 * vg2;
        }
    }
    const float SC = 0.011048543456039804f;          // EPS / sqrt(256)
    agg_s16[(size_t)n * 256 + f]       = (_Float16)(as0 * SC);
    agg_s16[(size_t)n * 256 + 128 + f] = (_Float16)(as1 * SC);
    _Float16* av = agg_v16 + (size_t)n * 768;
    av[0 * 256 + f]       = (_Float16)(av00 * SC);
    av[0 * 256 + 128 + f] = (_Float16)(av10 * SC);
    av[1 * 256 + f]       = (_Float16)(av01 * SC);
    av[1 * 256 + 128 + f] = (_Float16)(av11 * SC);
    av[2 * 256 + f]       = (_Float16)(av02 * SC);
    av[2 * 256 + 128 + f] = (_Float16)(av12 * SC);
}

// ---------------------------------------------------------------------------
// k_post: fused symmetric contraction + post GEMM + MFMA readout.
// ---------------------------------------------------------------------------
__global__ __launch_bounds__(256) void k_post(
    const float* __restrict__ s2, const float* __restrict__ v2,
    const float* __restrict__ Wsc, const int* __restrict__ counts,
    const _Float16* __restrict__ Wpost_t, const float* __restrict__ selfc,
    const _Float16* __restrict__ Wro1t, const float* __restrict__ Wro2,
    float* __restrict__ out)
{
    __shared__ _Float16 Bl[128 * 136];
    __shared__ _Float16 Al[128 * 136];   // sc16, then reused as sfeat16
    __shared__ float shr[128 * 16];
    const int t = threadIdx.x;
    const int row0 = blockIdx.x * 128;
    const float isf = 0.08838834764831845f;

    for (int idx = t; idx < 128 * 16; idx += 256) {
        int g = idx >> 4, kk = (idx & 15) * 8;
        *(v8h*)(Bl + g * 136 + kk) = *(const v8h*)(Wpost_t + g * 128 + kk);
    }

    // fused contract -> Al fp16 (A operand of post GEMM)
    #pragma unroll 4
    for (int i = 0; i < 16; ++i) {
        int idx = t + i * 256;           // r*32 + c4
        int r = idx >> 5, c4 = idx & 31;
        int rc = min(row0 + r, N_NODES - 1);
        float4 s4 = *(const float4*)(s2 + (size_t)rc * 128 + c4 * 4);
        float4 a0 = *(const float4*)(v2 + ((size_t)rc * 3 + 0) * 128 + c4 * 4);
        float4 a1 = *(const float4*)(v2 + ((size_t)rc * 3 + 1) * 128 + c4 * 4);
        float4 a2 = *(const float4*)(v2 + ((size_t)rc * 3 + 2) * 128 + c4 * 4);
        const float* w = Wsc + (size_t)species_of(rc, counts) * 640 + c4 * 4;
        float4 w0 = *(const float4*)(w);
        float4 w1 = *(const float4*)(w + 128);
        float4 w2 = *(const float4*)(w + 256);
        float4 w3 = *(const float4*)(w + 384);
        float4 w4 = *(const float4*)(w + 512);
        v4h r16;
        {
            float s = s4.x, vv = a0.x*a0.x + a1.x*a1.x + a2.x*a2.x;
            r16[0] = (_Float16)(w0.x*s + w1.x*(s*s) + w2.x*vv + w3.x*(s*s*s) + w4.x*(s*vv));
        }
        {
            float s = s4.y, vv = a0.y*a0.y + a1.y*a1.y + a2.y*a2.y;
            r16[1] = (_Float16)(w0.y*s + w1.y*(s*s) + w2.y*vv + w3.y*(s*s*s) + w4.y*(s*vv));
        }
        {
            float s = s4.z, vv = a0.z*a0.z + a1.z*a1.z + a2.z*a2.z;
            r16[2] = (_Float16)(w0.z*s + w1.z*(s*s) + w2.z*vv + w3.z*(s*s*s) + w4.z*(s*vv));
        }
        {
            float s = s4.w, vv = a0.w*a0.w + a1.w*a1.w + a2.w*a2.w;
            r16[3] = (_Float16)(w0.w*s + w1.w*(s*s) + w2.w*vv + w3.w*(s*s*s) + w4.w*(s*vv));
        }
        *(v4h*)(Al + r * 136 + c4 * 4) = r16;
    }
    __syncthreads();

    const int lane = t & 63;
    const int w = t >> 6;
    const int c = lane & 15;
    const int q = lane >> 4;

    // post GEMM: feats-pre = Al @ Wpost_t
    v4f acc[2][8];
    #pragma unroll
    for (int mi = 0; mi < 2; ++mi)
        #pragma unroll
        for (int nt = 0; nt < 8; ++nt)
            acc[mi][nt] = (v4f){0.f, 0.f, 0.f, 0.f};

    for (int ch = 0; ch < 4; ++ch) {
        v8h a[2];
        #pragma unroll
        for (int mi = 0; mi < 2; ++mi)
            a[mi] = *(const v8h*)(Al + ((2 * w + mi) * 16 + c) * 136 + ch * 32 + q * 8);
        #pragma unroll
        for (int nt = 0; nt < 8; ++nt) {
            v8h b = *(const v8h*)(Bl + (nt * 16 + c) * 136 + ch * 32 + q * 8);
            acc[0][nt] = __builtin_amdgcn_mfma_f32_16x16x32_f16(a[0], b, acc[0][nt], 0, 0, 0);
            acc[1][nt] = __builtin_amdgcn_mfma_f32_16x16x32_f16(a[1], b, acc[1][nt], 0, 0, 0);
        }
    }
    __syncthreads();                     // all waves done reading Al

    // epilogue: feats -> out + Al (fp16, for readout)
    #pragma unroll
    for (int mi = 0; mi < 2; ++mi) {
        #pragma unroll
        for (int r = 0; r < 4; ++r) {
            int row = row0 + (2 * w + mi) * 16 + q * 4 + r;
            int rl = (2 * w + mi) * 16 + q * 4 + r;
            if (row < N_NODES) {
                #pragma unroll
                for (int nt = 0; nt < 8; ++nt) {
                    int col = nt * 16 + c;
                    float feat = acc[mi][nt][r] * isf + selfc[(size_t)row * 128 + col];
                    out[N_NODES + (size_t)row * 128 + col] = feat;
                    Al[rl * 136 + col] = (_Float16)feat;
                }
            } else {
                #pragma unroll
                for (int nt = 0; nt < 8; ++nt) Al[rl * 136 + nt * 16 + c] = (_Float16)0.f;
            }
        }
    }
    __syncthreads();

    // readout GEMM: hr = feats @ Wro1t  (M=128, N=16, K=128)
    v4f hacc[2];
    hacc[0] = (v4f){0.f, 0.f, 0.f, 0.f};
    hacc[1] = (v4f){0.f, 0.f, 0.f, 0.f};
    for (int ch = 0; ch < 4; ++ch) {
        v8h b = *(const v8h*)(Wro1t + c * 128 + ch * 32 + q * 8);
        #pragma unroll
        for (int mi = 0; mi < 2; ++mi) {
            v8h a = *(const v8h*)(Al + ((2 * w + mi) * 16 + c) * 136 + ch * 32 + q * 8);
            hacc[mi] = __builtin_amdgcn_mfma_f32_16x16x32_f16(a, b, hacc[mi], 0, 0, 0);
        }
    }
    #pragma unroll
    for (int mi = 0; mi < 2; ++mi)
        #pragma unroll
        for (int r = 0; r < 4; ++r) {
            int rl = (2 * w + mi) * 16 + q * 4 + r;
            shr[rl * 16 + c] = nsilu(hacc[mi][r] * isf);
        }
    __syncthreads();

    if (t < 128 && row0 + t < N_NODES) {
        float a = 0;
        #pragma unroll
        for (int j = 0; j < 16; ++j) a += shr[t * 16 + j] * Wro2[j];
        out[row0 + t] = a * 0.25f;       // 1/sqrt(16)
    }
}

// ---------------------------------------------------------------------------

extern "C" void kernel_launch(void* const* d_in, const int* in_sizes, int n_in,
                              void* d_out, int out_size, void* d_ws, size_t ws_size,
                              hipStream_t stream) {
    const float* vectors      = (const float*)d_in[0];
    const float* node_scalars = (const float*)d_in[1];
    const float* node_vectors = (const float*)d_in[2];
    const float* radial       = (const float*)d_in[3];
    const float* W_up_s       = (const float*)d_in[4];
    const float* W_up_v       = (const float*)d_in[5];
    const float* W1 = (const float*)d_in[6];
    const float* b1 = (const float*)d_in[7];
    const float* W2 = (const float*)d_in[8];
    const float* b2 = (const float*)d_in[9];
    const float* W3 = (const float*)d_in[10];
    const float* b3 = (const float*)d_in[11];
    const float* W4 = (const float*)d_in[12];
    const float* b4 = (const float*)d_in[13];
    const float* Wds  = (const float*)d_in[14];
    const float* Wdv  = (const float*)d_in[15];
    const float* Wz   = (const float*)d_in[16];
    const float* Wsc  = (const float*)d_in[17];
    const float* Wpost= (const float*)d_in[18];
    const float* Wro1 = (const float*)d_in[19];
    const float* Wro2 = (const float*)d_in[20];
    const int* senders   = (const int*)d_in[21];
    const int* receivers = (const int*)d_in[22];
    const int* counts    = (const int*)d_in[23];
    float* out = (float*)d_out;

    const size_t NF = (size_t)N_NODES * F;

    char* base = (char*)d_ws;
    // mix (CSR-ordered, dead after gather) overlays s2/v2.
    _Float16* mix = (_Float16*)base;                 // E*512 fp16
    float* s2   = (float*)base;                      // N*128 fp32
    float* v2   = s2 + NF;                           // 3N*128 fp32

    char* p = base + (size_t)N_EDGES * 512 * 2;
    float4* yq     = (float4*)p;          p += (size_t)N_EDGES * 16;
    _Float16* ns16 = (_Float16*)p;        p += NF * 2;
    _Float16* nv16 = (_Float16*)p;        p += 3 * NF * 2;
    _Float16* s16  = (_Float16*)p;        p += NF * 2;
    _Float16* v16  = (_Float16*)p;        p += 3 * NF * 2;
    float* selfc   = (float*)p;           p += NF * 4;
    _Float16* agg_s16 = (_Float16*)p;     p += 2 * NF * 2;
    _Float16* agg_v16 = (_Float16*)p;     p += 6 * NF * 2;
    int* deg    = (int*)p;                p += N_NODES * 4;
    int* offs   = (int*)p;                p += (N_NODES + 1) * 4 + 12;  // pad
    int* cursor = (int*)p;                p += N_NODES * 4;
    _Float16* W2t = (_Float16*)p;         p += 4096 * 2;
    _Float16* W3t = (_Float16*)p;         p += 4096 * 2;
    _Float16* W4t = (_Float16*)p;         p += 32768 * 2;
    float* b4p    = (float*)p;            p += 512 * 4;
    _Float16* Wup_s_t = (_Float16*)p;     p += 16384 * 2;
    _Float16* Wup_v_t = (_Float16*)p;     p += 16384 * 2;
    _Float16* Wz_t    = (_Float16*)p;     p += 65536 * 2;
    _Float16* Wds_t   = (_Float16*)p;     p += 32768 * 2;
    _Float16* Wdv_t   = (_Float16*)p;     p += 32768 * 2;
    _Float16* Wpost_t = (_Float16*)p;     p += 16384 * 2;
    _Float16* Wro1t   = (_Float16*)p;     p += 2048 * 2;

    // re_csr (E*8 floats) ALIASES agg_v16: written by k_fill, read by k_mlp;
    // agg_v16 written only by k_gather which runs strictly after k_mlp.
    float4* re_csr = (float4*)agg_v16;

    hipMemsetAsync(deg, 0, N_NODES * sizeof(int), stream);

    k_setup<<<21499, 256, 0, stream>>>(
        receivers, deg, W2, W3, W4, b4, W_up_s, W_up_v, Wz, Wds, Wdv, Wpost, Wro1,
        W2t, W3t, W4t, b4p, Wup_s_t, Wup_v_t, Wz_t, Wds_t, Wdv_t, Wpost_t, Wro1t,
        node_scalars, node_vectors, ns16, nv16);

    k_scan<<<1, 1024, 0, stream>>>(deg, offs, cursor);

    k_fill<<<(N_EDGES + 255) / 256, 256, 0, stream>>>(
        receivers, senders, vectors, radial, cursor, yq, re_csr);

    k_gemm_up<<<dim3(235, 3), 256, 0, stream>>>(
        ns16, nv16, Wup_s_t, Wup_v_t, Wz_t, counts, s16, v16, selfc);

    k_mlp<<<N_EDGES / TE, 256, 0, stream>>>(
        (const float*)re_csr, W1, b1, W2t, b2, W3t, b3, W4t, b4p, mix);

    k_gather<<<N_NODES, 128, 0, stream>>>(
        mix, yq, s16, v16, offs, agg_s16, agg_v16);

    k_gemm_down<<<dim3(235, 2), 256, 0, stream>>>(
        agg_s16, agg_v16, Wds_t, Wdv_t, counts, s2, v2);

    k_post<<<(N_NODES + 127) / 128, 256, 0, stream>>>(
        s2, v2, Wsc, counts, Wpost_t, selfc, Wro1t, Wro2, out);
}